// Round 1
// baseline (11686.280 us; speedup 1.0000x reference)
//
#include <hip/hip_runtime.h>
#include <math.h>

// Problem constants
constexpr int cB = 8, cT = 510, cNH = 12, cEX = 768, cVOC = 256, cNBLK = 11, cHD = 64;
constexpr int cMR = cB * cT;        // 4080 rows
constexpr int cKH = cT * cEX;       // 391680 (per-batch flattened dim for head)

// ---------------- embedding: x[b,t,:] = relu(lin_w[tok] + lin_w[2+t] + lin_b) ----------------
__global__ __launch_bounds__(256) void embed_kernel(
    const int* __restrict__ idx, const float* __restrict__ lin_w,
    const float* __restrict__ lin_b, float* __restrict__ x)
{
    int row = blockIdx.x;            // b*T + t
    int t = row % cT;
    int tok = idx[row] & 1;
    const float* wt = lin_w + (size_t)tok * cEX;
    const float* wp = lin_w + (size_t)(2 + t) * cEX;
    float* xr = x + (size_t)row * cEX;
    for (int j = threadIdx.x; j < cEX; j += 256) {
        float val = wt[j] + wp[j] + lin_b[j];
        xr[j] = fmaxf(val, 0.0f);
    }
}

// ---------------- layernorm over last dim (768) ----------------
__global__ __launch_bounds__(256) void ln_kernel(
    const float* __restrict__ in, const float* __restrict__ s,
    const float* __restrict__ bsh, float* __restrict__ out)
{
    int row = blockIdx.x;
    int tid = threadIdx.x;
    const float* xr = in + (size_t)row * cEX;
    float sum = 0.0f, sq = 0.0f;
    for (int j = tid; j < cEX; j += 256) {
        float v = xr[j];
        sum += v; sq += v * v;
    }
    for (int off = 32; off > 0; off >>= 1) {
        sum += __shfl_down(sum, off, 64);
        sq  += __shfl_down(sq, off, 64);
    }
    __shared__ float ssum[4], ssq[4];
    __shared__ float smean, srstd;
    int w = tid >> 6, lane = tid & 63;
    if (lane == 0) { ssum[w] = sum; ssq[w] = sq; }
    __syncthreads();
    if (tid == 0) {
        float S = ssum[0] + ssum[1] + ssum[2] + ssum[3];
        float Q = ssq[0] + ssq[1] + ssq[2] + ssq[3];
        float mean = S * (1.0f / cEX);
        float var = Q * (1.0f / cEX) - mean * mean;
        smean = mean;
        srstd = rsqrtf(var + 1e-5f);
    }
    __syncthreads();
    float mean = smean, rstd = srstd;
    float* outr = out + (size_t)row * cEX;
    for (int j = tid; j < cEX; j += 256) {
        outr[j] = (xr[j] - mean) * rstd * s[j] + bsh[j];
    }
}

// ---------------- fp32 tiled GEMM: C[M,N] = A[M,K] @ W[K,N] + bias (+relu) (+resid) ----------------
template<bool RELU, bool RESID>
__global__ __launch_bounds__(256) void gemm64(
    const float* __restrict__ A, const float* __restrict__ W,
    const float* __restrict__ bias, const float* __restrict__ resid,
    float* __restrict__ C, int M, int N, int K)
{
    __shared__ float As[16][64];     // As[k][m]
    __shared__ float Bs[16][64];     // Bs[k][n]
    const int tid = threadIdx.x;
    const int bn = blockIdx.x * 64;
    const int bm = blockIdx.y * 64;
    const int tx = tid & 15, ty = tid >> 4;
    const int arow = tid >> 2, acol = (tid & 3) * 4;
    const int brow = tid >> 4, bcol = (tid & 15) * 4;
    float acc[4][4] = {};
    for (int k0 = 0; k0 < K; k0 += 16) {
        float4 av = make_float4(0.f, 0.f, 0.f, 0.f);
        int gm = bm + arow;
        if (gm < M) av = *(const float4*)(A + (size_t)gm * K + k0 + acol);
        As[acol + 0][arow] = av.x;
        As[acol + 1][arow] = av.y;
        As[acol + 2][arow] = av.z;
        As[acol + 3][arow] = av.w;
        *(float4*)&Bs[brow][bcol] =
            *(const float4*)(W + (size_t)(k0 + brow) * N + bn + bcol);
        __syncthreads();
#pragma unroll
        for (int kk = 0; kk < 16; ++kk) {
            float4 a = *(const float4*)&As[kk][ty * 4];
            float4 b = *(const float4*)&Bs[kk][tx * 4];
            float ar[4] = {a.x, a.y, a.z, a.w};
            float br[4] = {b.x, b.y, b.z, b.w};
#pragma unroll
            for (int i = 0; i < 4; ++i)
#pragma unroll
                for (int j = 0; j < 4; ++j)
                    acc[i][j] = fmaf(ar[i], br[j], acc[i][j]);
        }
        __syncthreads();
    }
#pragma unroll
    for (int i = 0; i < 4; ++i) {
        int gm = bm + ty * 4 + i;
        if (gm >= M) break;
#pragma unroll
        for (int j = 0; j < 4; ++j) {
            int gn = bn + tx * 4 + j;
            float v = acc[i][j] + bias[gn];
            if (RELU) v = fmaxf(v, 0.0f);
            if (RESID) v += resid[(size_t)gm * N + gn];
            C[(size_t)gm * N + gn] = v;
        }
    }
}

// ---------------- fused causal attention (flash-style, fp32) ----------------
// grid (16 q-tiles, 12 heads, 8 batch), 256 threads.
// thread t: r = t>>3 (q-row in tile), g = t&7 (owns O cols g*8..g*8+7, scores k = g+8i)
__global__ __launch_bounds__(256) void attn_kernel(
    const float* __restrict__ q, const float* __restrict__ k,
    const float* __restrict__ v, float* __restrict__ y)
{
    const int qt = blockIdx.x;
    const int h = blockIdx.y;
    const int b = blockIdx.z;
    __shared__ float Qs[32][68], Ks[32][68], Vs[32][68];
    __shared__ float Ss[32][32];
    const int tid = threadIdx.x;
    const int r = tid >> 3, g = tid & 7;

#pragma unroll
    for (int i = 0; i < 2; ++i) {
        int idx4 = tid + 256 * i;          // 0..511 float4 slots (32 rows x 16 f4)
        int rr = idx4 >> 4, cc = (idx4 & 15) * 4;
        int qrow = qt * 32 + rr;
        int qc = qrow < cT ? qrow : cT - 1;
        *(float4*)&Qs[rr][cc] =
            *(const float4*)(q + ((size_t)(b * cT + qc)) * cEX + h * cHD + cc);
    }

    float O[8] = {};
    float m = -1e30f, l = 0.0f;
    const int qg = qt * 32 + r;

    for (int kt = 0; kt <= qt; ++kt) {
        __syncthreads();
#pragma unroll
        for (int i = 0; i < 2; ++i) {
            int idx4 = tid + 256 * i;
            int rr = idx4 >> 4, cc = (idx4 & 15) * 4;
            int krow = kt * 32 + rr;
            int kc = krow < cT ? krow : cT - 1;
            *(float4*)&Ks[rr][cc] =
                *(const float4*)(k + ((size_t)(b * cT + kc)) * cEX + h * cHD + cc);
            *(float4*)&Vs[rr][cc] =
                *(const float4*)(v + ((size_t)(b * cT + kc)) * cEX + h * cHD + cc);
        }
        __syncthreads();

        float s[4] = {};
#pragma unroll
        for (int d = 0; d < 64; d += 4) {
            float4 qv = *(const float4*)&Qs[r][d];
#pragma unroll
            for (int i = 0; i < 4; ++i) {
                float4 kv = *(const float4*)&Ks[g + 8 * i][d];
                s[i] += qv.x * kv.x + qv.y * kv.y + qv.z * kv.z + qv.w * kv.w;
            }
        }
#pragma unroll
        for (int i = 0; i < 4; ++i) {
            int kg = kt * 32 + g + 8 * i;
            s[i] = (kg <= qg && kg < cT) ? s[i] * 0.125f : -1e30f;
        }
        float tmax = fmaxf(fmaxf(s[0], s[1]), fmaxf(s[2], s[3]));
        tmax = fmaxf(tmax, __shfl_xor(tmax, 1, 8));
        tmax = fmaxf(tmax, __shfl_xor(tmax, 2, 8));
        tmax = fmaxf(tmax, __shfl_xor(tmax, 4, 8));
        float mnew = fmaxf(m, tmax);
        float p[4];
        float psum = 0.0f;
#pragma unroll
        for (int i = 0; i < 4; ++i) { p[i] = __expf(s[i] - mnew); psum += p[i]; }
        psum += __shfl_xor(psum, 1, 8);
        psum += __shfl_xor(psum, 2, 8);
        psum += __shfl_xor(psum, 4, 8);
        float scale = __expf(m - mnew);
        l = l * scale + psum;
        m = mnew;
#pragma unroll
        for (int j = 0; j < 8; ++j) O[j] *= scale;
#pragma unroll
        for (int i = 0; i < 4; ++i) Ss[r][g + 8 * i] = p[i];
        __syncthreads();
#pragma unroll
        for (int kk = 0; kk < 32; ++kk) {
            float pk = Ss[r][kk];
            float4 v0 = *(const float4*)&Vs[kk][g * 8];
            float4 v1 = *(const float4*)&Vs[kk][g * 8 + 4];
            O[0] += pk * v0.x; O[1] += pk * v0.y; O[2] += pk * v0.z; O[3] += pk * v0.w;
            O[4] += pk * v1.x; O[5] += pk * v1.y; O[6] += pk * v1.z; O[7] += pk * v1.w;
        }
    }
    if (qg < cT) {
        float invl = 1.0f / l;
        float* yr = y + ((size_t)(b * cT + qg)) * cEX + h * cHD + g * 8;
#pragma unroll
        for (int j = 0; j < 8; ++j) yr[j] = O[j] * invl;
    }
}

// ---------------- head: partial K-chunk products, then deterministic reduce ----------------
__global__ __launch_bounds__(256) void head_part_kernel(
    const float* __restrict__ xf, const float* __restrict__ hw, float* __restrict__ part)
{
    __shared__ float xs[8][1536];
    const int tid = threadIdx.x;
    const int k0 = blockIdx.x * 1536;
    for (int i = tid; i < 8 * 1536; i += 256) {
        int bb = i / 1536, kk = i - bb * 1536;
        xs[bb][kk] = xf[(size_t)bb * cKH + k0 + kk];
    }
    __syncthreads();
    float acc[8] = {};
    const float* wp = hw + (size_t)k0 * cVOC + tid;
    for (int kk = 0; kk < 1536; ++kk) {
        float w = wp[(size_t)kk * cVOC];
#pragma unroll
        for (int bb = 0; bb < 8; ++bb) acc[bb] += xs[bb][kk] * w;
    }
#pragma unroll
    for (int bb = 0; bb < 8; ++bb)
        part[((size_t)blockIdx.x * 8 + bb) * cVOC + tid] = acc[bb];
}

__global__ __launch_bounds__(256) void head_reduce_kernel(
    const float* __restrict__ part, const float* __restrict__ hb, float* __restrict__ out)
{
    int i = blockIdx.x * 256 + threadIdx.x;  // 0..2047
    int bb = i >> 8, vv = i & 255;
    float acc = hb[vv];
    for (int c = 0; c < 255; ++c) acc += part[((size_t)c * 8 + bb) * 256 + vv];
    out[i] = acc;
}

// ---------------- launch ----------------
extern "C" void kernel_launch(void* const* d_in, const int* in_sizes, int n_in,
                              void* d_out, int out_size, void* d_ws, size_t ws_size,
                              hipStream_t stream) {
    (void)in_sizes; (void)n_in; (void)out_size; (void)ws_size;
    const int*   idx    = (const int*)d_in[0];
    const float* lin_w  = (const float*)d_in[1];
    const float* lin_b  = (const float*)d_in[2];
    const float* ln1_s  = (const float*)d_in[3];
    const float* ln1_b  = (const float*)d_in[4];
    const float* qw     = (const float*)d_in[5];
    const float* qbias  = (const float*)d_in[6];
    const float* kw     = (const float*)d_in[7];
    const float* kbias  = (const float*)d_in[8];
    const float* vw     = (const float*)d_in[9];
    const float* vbias  = (const float*)d_in[10];
    const float* ew     = (const float*)d_in[11];
    const float* ebias  = (const float*)d_in[12];
    const float* ln2_s  = (const float*)d_in[13];
    const float* ln2_b  = (const float*)d_in[14];
    const float* m1w    = (const float*)d_in[15];
    const float* m1b    = (const float*)d_in[16];
    const float* m2w    = (const float*)d_in[17];
    const float* m2b    = (const float*)d_in[18];
    const float* lnf_s  = (const float*)d_in[19];
    const float* lnf_b  = (const float*)d_in[20];
    const float* head_w = (const float*)d_in[21];
    const float* head_b = (const float*)d_in[22];
    float* out = (float*)d_out;

    const size_t act = (size_t)cMR * cEX;       // 3,133,440 floats
    float* ws   = (float*)d_ws;
    float* x    = ws;                // residual stream
    float* h    = x + act;           // LN1 out; also attention y; also final LN out
    float* qbuf = h + act;           // q; also LN2 out (h2)
    float* kbuf = qbuf + act;
    float* vbuf = kbuf + act;
    float* u    = vbuf + act;        // MLP hidden [4080,3072]; also head partials
    float* part = u;

    embed_kernel<<<cMR, 256, 0, stream>>>(idx, lin_w, lin_b, x);

    dim3 g768(12, 64), g3072(48, 64);
    for (int blk = 0; blk < cNBLK; ++blk) {
        size_t wo = (size_t)blk * cEX * cEX;
        size_t bo = (size_t)blk * cEX;
        ln_kernel<<<cMR, 256, 0, stream>>>(x, ln1_s + bo, ln1_b + bo, h);
        gemm64<false, false><<<g768, 256, 0, stream>>>(h, qw + wo, qbias + bo, nullptr, qbuf, cMR, cEX, cEX);
        gemm64<false, false><<<g768, 256, 0, stream>>>(h, kw + wo, kbias + bo, nullptr, kbuf, cMR, cEX, cEX);
        gemm64<false, false><<<g768, 256, 0, stream>>>(h, vw + wo, vbias + bo, nullptr, vbuf, cMR, cEX, cEX);
        attn_kernel<<<dim3(16, cNH, cB), 256, 0, stream>>>(qbuf, kbuf, vbuf, h);
        gemm64<false, true><<<g768, 256, 0, stream>>>(h, ew + wo, ebias + bo, x, x, cMR, cEX, cEX);
        ln_kernel<<<cMR, 256, 0, stream>>>(x, ln2_s + bo, ln2_b + bo, qbuf);
        gemm64<true, false><<<g3072, 256, 0, stream>>>(qbuf, m1w + (size_t)blk * cEX * 4 * cEX,
                                                       m1b + (size_t)blk * 4 * cEX, nullptr, u,
                                                       cMR, 4 * cEX, cEX);
        gemm64<false, true><<<g768, 256, 0, stream>>>(u, m2w + (size_t)blk * 4 * cEX * cEX,
                                                      m2b + bo, x, x, cMR, cEX, 4 * cEX);
    }
    ln_kernel<<<cMR, 256, 0, stream>>>(x, lnf_s, lnf_b, h);
    head_part_kernel<<<255, 256, 0, stream>>>(h, head_w, part);
    head_reduce_kernel<<<8, 256, 0, stream>>>(part, head_b, out);
}

// Round 2
// 4101.664 us; speedup vs baseline: 2.8492x; 2.8492x over previous
//
#include <hip/hip_runtime.h>
#include <hip/hip_bf16.h>
#include <math.h>

constexpr int cB = 8, cT = 510, cNH = 12, cEX = 768, cVOC = 256, cNBLK = 11, cHD = 64;
constexpr int cMR = cB * cT;     // 4080 real rows
constexpr int cMP = 4096;        // padded rows (multiple of 128)
constexpr int cKH = cT * cEX;    // 391680
constexpr int cQKV = 3 * cEX;    // 2304

typedef __attribute__((ext_vector_type(8))) short bf16x8;
typedef __attribute__((ext_vector_type(4))) float f32x4;
using bf16 = __hip_bfloat16;

// ---------------- async global->LDS 16B ----------------
__device__ inline void gload16(const void* g, void* l) {
    __builtin_amdgcn_global_load_lds((const __attribute__((address_space(1))) unsigned int*)g,
                                     (__attribute__((address_space(3))) unsigned int*)l, 16, 0, 0);
}

// ---------------- embedding (writes zeros to pad rows) ----------------
__global__ __launch_bounds__(256) void embed_kernel(
    const int* __restrict__ idx, const float* __restrict__ lin_w,
    const float* __restrict__ lin_b, float* __restrict__ x)
{
    int row = blockIdx.x;
    float* xr = x + (size_t)row * cEX;
    if (row >= cMR) {
        for (int j = threadIdx.x; j < cEX; j += 256) xr[j] = 0.0f;
        return;
    }
    int t = row % cT;
    int tok = idx[row] & 1;
    const float* wt = lin_w + (size_t)tok * cEX;
    const float* wp = lin_w + (size_t)(2 + t) * cEX;
    for (int j = threadIdx.x; j < cEX; j += 256) {
        float val = wt[j] + wp[j] + lin_b[j];
        xr[j] = fmaxf(val, 0.0f);
    }
}

// ---------------- layernorm, templated output dtype ----------------
template<typename OUT>
__global__ __launch_bounds__(256) void ln_kernel(
    const float* __restrict__ in, const float* __restrict__ s,
    const float* __restrict__ bsh, OUT* __restrict__ out)
{
    int row = blockIdx.x;
    int tid = threadIdx.x;
    const float* xr = in + (size_t)row * cEX;
    float sum = 0.0f, sq = 0.0f;
    for (int j = tid; j < cEX; j += 256) {
        float v = xr[j];
        sum += v; sq += v * v;
    }
    for (int off = 32; off > 0; off >>= 1) {
        sum += __shfl_down(sum, off, 64);
        sq  += __shfl_down(sq, off, 64);
    }
    __shared__ float ssum[4], ssq[4];
    __shared__ float smean, srstd;
    int w = tid >> 6, lane = tid & 63;
    if (lane == 0) { ssum[w] = sum; ssq[w] = sq; }
    __syncthreads();
    if (tid == 0) {
        float S = ssum[0] + ssum[1] + ssum[2] + ssum[3];
        float Q = ssq[0] + ssq[1] + ssq[2] + ssq[3];
        float mean = S * (1.0f / cEX);
        float var = Q * (1.0f / cEX) - mean * mean;
        smean = mean;
        srstd = rsqrtf(var + 1e-5f);
    }
    __syncthreads();
    float mean = smean, rstd = srstd;
    OUT* outr = out + (size_t)row * cEX;
    for (int j = tid; j < cEX; j += 256) {
        float v = (xr[j] - mean) * rstd * s[j] + bsh[j];
        if constexpr (sizeof(OUT) == 2) outr[j] = __float2bfloat16(v);
        else                            outr[j] = v;
    }
}

// ---------------- weight transpose + fp32->bf16: W[K][N] -> WT[N][K] ----------------
// grid (N/32, K/32, NBLK)
__global__ __launch_bounds__(256) void transpose_w(
    const float* __restrict__ W, bf16* __restrict__ WT,
    int K, int N, size_t w_stride, size_t wt_stride, int wt_row_off)
{
    __shared__ float t[32][33];
    const float* Wb = W + (size_t)blockIdx.z * w_stride;
    bf16* WTb = WT + (size_t)blockIdx.z * wt_stride;
    int n0 = blockIdx.x * 32, k0 = blockIdx.y * 32;
    int c = threadIdx.x & 31, ty = threadIdx.x >> 5;
#pragma unroll
    for (int it = 0; it < 4; ++it) {
        int r = ty + it * 8;
        t[r][c] = Wb[(size_t)(k0 + r) * N + n0 + c];
    }
    __syncthreads();
#pragma unroll
    for (int it = 0; it < 4; ++it) {
        int a = ty + it * 8;   // n-index within tile
        WTb[(size_t)(wt_row_off + n0 + a) * K + k0 + c] = __float2bfloat16(t[c][a]);
    }
}

// ---------------- concat q/k/v biases into [NBLK][2304] ----------------
__global__ __launch_bounds__(256) void concat_bias(
    const float* __restrict__ qb, const float* __restrict__ kb,
    const float* __restrict__ vb, float* __restrict__ qkvb)
{
    int i = blockIdx.x * 256 + threadIdx.x;
    if (i >= cNBLK * cQKV) return;
    int blk = i / cQKV, c = i - blk * cQKV;
    const float* src; int cc = c;
    if (c < cEX)            { src = qb; }
    else if (c < 2 * cEX)   { src = kb; cc = c - cEX; }
    else                    { src = vb; cc = c - 2 * cEX; }
    qkvb[i] = src[(size_t)blk * cEX + cc];
}

// ---------------- MFMA GEMM: C[M,N] = A[M,K](bf16) @ BT[N,K](bf16)^T + bias ----------------
// m97 structure: single-buffer LDS, global_load_lds(16B), ds_read_b128 frags,
// 2 barriers per K-step. 4 waves in 2x2; wave tile (FM*16)x(FN*16).
template<int FM, int FN, bool RELU, bool RESID, bool OUTBF16>
__global__ __launch_bounds__(256) void gemm_mfma(
    const short* __restrict__ A, const short* __restrict__ BT,
    const float* __restrict__ bias, const float* __restrict__ resid,
    void* __restrict__ Cout, int K, int N)
{
    constexpr int BM = FM * 32, BN = FN * 32;
    __shared__ short ldsA[BM * 32];
    __shared__ short ldsB[BN * 32];
    const int tid = threadIdx.x;
    const int lane = tid & 63, wid = tid >> 6;
    const int wm = wid >> 1, wn = wid & 1;
    const int bm = blockIdx.y * BM, bn = blockIdx.x * BN;

    f32x4 acc[FM][FN];
#pragma unroll
    for (int i = 0; i < FM; ++i)
#pragma unroll
        for (int j = 0; j < FN; ++j)
            acc[i][j] = f32x4{0.f, 0.f, 0.f, 0.f};

    constexpr int CA = BM / 64, CB = BN / 64;   // gload16 per thread for A / B
    const int li = lane & 15, gk = lane >> 4;

    for (int k0 = 0; k0 < K; k0 += 32) {
#pragma unroll
        for (int i = 0; i < CA; ++i) {
            int s = i * 256 + tid;
            int r = s >> 2, w = s & 3;
            gload16(A + (size_t)(bm + r) * K + k0 + w * 8,
                    (char*)ldsA + (size_t)(i * 256 + wid * 64) * 16);
        }
#pragma unroll
        for (int i = 0; i < CB; ++i) {
            int s = i * 256 + tid;
            int r = s >> 2, w = s & 3;
            gload16(BT + (size_t)(bn + r) * K + k0 + w * 8,
                    (char*)ldsB + (size_t)(i * 256 + wid * 64) * 16);
        }
        __syncthreads();   // compiler drains vmcnt(0) before barrier -> LDS ready

        bf16x8 af[FM], bf_[FN];
#pragma unroll
        for (int mi = 0; mi < FM; ++mi)
            af[mi] = *(const bf16x8*)&ldsA[(wm * FM * 16 + mi * 16 + li) * 32 + gk * 8];
#pragma unroll
        for (int ni = 0; ni < FN; ++ni)
            bf_[ni] = *(const bf16x8*)&ldsB[(wn * FN * 16 + ni * 16 + li) * 32 + gk * 8];
#pragma unroll
        for (int mi = 0; mi < FM; ++mi)
#pragma unroll
            for (int ni = 0; ni < FN; ++ni)
                acc[mi][ni] = __builtin_amdgcn_mfma_f32_16x16x32_bf16(
                    af[mi], bf_[ni], acc[mi][ni], 0, 0, 0);
        __syncthreads();   // protect LDS from next-iter staging
    }

    // epilogue: C/D layout col=lane&15, row=(lane>>4)*4+j  [m89-verified]
#pragma unroll
    for (int mi = 0; mi < FM; ++mi) {
#pragma unroll
        for (int ni = 0; ni < FN; ++ni) {
            int col = bn + wn * FN * 16 + ni * 16 + li;
            float bv = bias[col];
#pragma unroll
            for (int j = 0; j < 4; ++j) {
                int row = bm + wm * FM * 16 + mi * 16 + gk * 4 + j;
                float v = acc[mi][ni][j] + bv;
                if (RELU) v = fmaxf(v, 0.0f);
                if (RESID) v += resid[(size_t)row * N + col];
                if (OUTBF16)
                    ((bf16*)Cout)[(size_t)row * N + col] = __float2bfloat16(v);
                else
                    ((float*)Cout)[(size_t)row * N + col] = v;
            }
        }
    }
}

// ---------------- fused causal attention (fp32, reads fused qkv, writes bf16) ----------------
__global__ __launch_bounds__(256) void attn_kernel(
    const float* __restrict__ qkv, bf16* __restrict__ y)
{
    const int qt = blockIdx.x;
    const int h = blockIdx.y;
    const int b = blockIdx.z;
    __shared__ float Qs[32][68], Ks[32][68], Vs[32][68];
    __shared__ float Ss[32][32];
    const int tid = threadIdx.x;
    const int r = tid >> 3, g = tid & 7;

#pragma unroll
    for (int i = 0; i < 2; ++i) {
        int idx4 = tid + 256 * i;
        int rr = idx4 >> 4, cc = (idx4 & 15) * 4;
        int qrow = qt * 32 + rr;
        int qc = qrow < cT ? qrow : cT - 1;
        *(float4*)&Qs[rr][cc] =
            *(const float4*)(qkv + ((size_t)(b * cT + qc)) * cQKV + h * cHD + cc);
    }

    float O[8] = {};
    float m = -1e30f, l = 0.0f;
    const int qg = qt * 32 + r;

    for (int kt = 0; kt <= qt; ++kt) {
        __syncthreads();
#pragma unroll
        for (int i = 0; i < 2; ++i) {
            int idx4 = tid + 256 * i;
            int rr = idx4 >> 4, cc = (idx4 & 15) * 4;
            int krow = kt * 32 + rr;
            int kc = krow < cT ? krow : cT - 1;
            const float* base = qkv + ((size_t)(b * cT + kc)) * cQKV + h * cHD + cc;
            *(float4*)&Ks[rr][cc] = *(const float4*)(base + cEX);
            *(float4*)&Vs[rr][cc] = *(const float4*)(base + 2 * cEX);
        }
        __syncthreads();

        float s[4] = {};
#pragma unroll
        for (int d = 0; d < 64; d += 4) {
            float4 qv = *(const float4*)&Qs[r][d];
#pragma unroll
            for (int i = 0; i < 4; ++i) {
                float4 kv = *(const float4*)&Ks[g + 8 * i][d];
                s[i] += qv.x * kv.x + qv.y * kv.y + qv.z * kv.z + qv.w * kv.w;
            }
        }
#pragma unroll
        for (int i = 0; i < 4; ++i) {
            int kg = kt * 32 + g + 8 * i;
            s[i] = (kg <= qg && kg < cT) ? s[i] * 0.125f : -1e30f;
        }
        float tmax = fmaxf(fmaxf(s[0], s[1]), fmaxf(s[2], s[3]));
        tmax = fmaxf(tmax, __shfl_xor(tmax, 1, 8));
        tmax = fmaxf(tmax, __shfl_xor(tmax, 2, 8));
        tmax = fmaxf(tmax, __shfl_xor(tmax, 4, 8));
        float mnew = fmaxf(m, tmax);
        float p[4];
        float psum = 0.0f;
#pragma unroll
        for (int i = 0; i < 4; ++i) { p[i] = __expf(s[i] - mnew); psum += p[i]; }
        psum += __shfl_xor(psum, 1, 8);
        psum += __shfl_xor(psum, 2, 8);
        psum += __shfl_xor(psum, 4, 8);
        float scale = __expf(m - mnew);
        l = l * scale + psum;
        m = mnew;
#pragma unroll
        for (int j = 0; j < 8; ++j) O[j] *= scale;
#pragma unroll
        for (int i = 0; i < 4; ++i) Ss[r][g + 8 * i] = p[i];
        __syncthreads();
#pragma unroll
        for (int kk = 0; kk < 32; ++kk) {
            float pk = Ss[r][kk];
            float4 v0 = *(const float4*)&Vs[kk][g * 8];
            float4 v1 = *(const float4*)&Vs[kk][g * 8 + 4];
            O[0] += pk * v0.x; O[1] += pk * v0.y; O[2] += pk * v0.z; O[3] += pk * v0.w;
            O[4] += pk * v1.x; O[5] += pk * v1.y; O[6] += pk * v1.z; O[7] += pk * v1.w;
        }
    }
    if (qg < cT) {
        float invl = 1.0f / l;
        bf16* yr = y + ((size_t)(b * cT + qg)) * cEX + h * cHD + g * 8;
#pragma unroll
        for (int j = 0; j < 8; ++j) yr[j] = __float2bfloat16(O[j] * invl);
    }
}

// ---------------- head (fp32, memory-bound on head_w) ----------------
__global__ __launch_bounds__(256) void head_part_kernel(
    const float* __restrict__ xf, const float* __restrict__ hw, float* __restrict__ part)
{
    __shared__ float xs[8][1536];
    const int tid = threadIdx.x;
    const int k0 = blockIdx.x * 1536;
    for (int i = tid; i < 8 * 1536; i += 256) {
        int bb = i / 1536, kk = i - bb * 1536;
        xs[bb][kk] = xf[(size_t)bb * cKH + k0 + kk];
    }
    __syncthreads();
    float acc[8] = {};
    const float* wp = hw + (size_t)k0 * cVOC + tid;
    for (int kk = 0; kk < 1536; ++kk) {
        float w = wp[(size_t)kk * cVOC];
#pragma unroll
        for (int bb = 0; bb < 8; ++bb) acc[bb] += xs[bb][kk] * w;
    }
#pragma unroll
    for (int bb = 0; bb < 8; ++bb)
        part[((size_t)blockIdx.x * 8 + bb) * cVOC + tid] = acc[bb];
}

__global__ __launch_bounds__(256) void head_reduce_kernel(
    const float* __restrict__ part, const float* __restrict__ hb, float* __restrict__ out)
{
    int i = blockIdx.x * 256 + threadIdx.x;
    int bb = i >> 8, vv = i & 255;
    float acc = hb[vv];
    for (int c = 0; c < 255; ++c) acc += part[((size_t)c * 8 + bb) * 256 + vv];
    out[i] = acc;
}

// ---------------- launch ----------------
extern "C" void kernel_launch(void* const* d_in, const int* in_sizes, int n_in,
                              void* d_out, int out_size, void* d_ws, size_t ws_size,
                              hipStream_t stream) {
    (void)in_sizes; (void)n_in; (void)out_size; (void)ws_size;
    const int*   idx    = (const int*)d_in[0];
    const float* lin_w  = (const float*)d_in[1];
    const float* lin_b  = (const float*)d_in[2];
    const float* ln1_s  = (const float*)d_in[3];
    const float* ln1_b  = (const float*)d_in[4];
    const float* qw     = (const float*)d_in[5];
    const float* qbias  = (const float*)d_in[6];
    const float* kw     = (const float*)d_in[7];
    const float* kbias  = (const float*)d_in[8];
    const float* vw     = (const float*)d_in[9];
    const float* vbias  = (const float*)d_in[10];
    const float* ew     = (const float*)d_in[11];
    const float* ebias  = (const float*)d_in[12];
    const float* ln2_s  = (const float*)d_in[13];
    const float* ln2_b  = (const float*)d_in[14];
    const float* m1w    = (const float*)d_in[15];
    const float* m1b    = (const float*)d_in[16];
    const float* m2w    = (const float*)d_in[17];
    const float* m2b    = (const float*)d_in[18];
    const float* lnf_s  = (const float*)d_in[19];
    const float* lnf_b  = (const float*)d_in[20];
    const float* head_w = (const float*)d_in[21];
    const float* head_b = (const float*)d_in[22];
    float* out = (float*)d_out;

    // ---- workspace carve-up ----
    float* x    = (float*)d_ws;                    // [cMP][768] fp32 residual
    float* qkv  = x + (size_t)cMP * cEX;           // [cMP][2304] fp32
    float* xf   = qkv + (size_t)cMP * cQKV;        // [cMP][768] fp32 final LN
    float* part = xf + (size_t)cMP * cEX;          // 255*8*256
    float* qkvb = part + 255 * 8 * 256;            // [NBLK][2304]
    bf16* h    = (bf16*)(qkvb + cNBLK * cQKV);     // [cMP][768] LN1 out
    bf16* h2   = h + (size_t)cMP * cEX;            // [cMP][768] LN2 out
    bf16* y    = h2 + (size_t)cMP * cEX;           // [cMP][768] attn out
    bf16* u    = y + (size_t)cMP * cEX;            // [cMP][3072] MLP hidden
    bf16* wqkvT = u + (size_t)cMP * 4 * cEX;       // [NBLK][2304][768]
    bf16* weT   = wqkvT + (size_t)cNBLK * cQKV * cEX;      // [NBLK][768][768]
    bf16* wm1T  = weT + (size_t)cNBLK * cEX * cEX;         // [NBLK][3072][768]
    bf16* wm2T  = wm1T + (size_t)cNBLK * cEX * 4 * cEX;    // [NBLK][768][3072]

    // ---- weight conversion (per launch; ~470MB traffic ≈ 80us) ----
    transpose_w<<<dim3(24, 24, cNBLK), 256, 0, stream>>>(qw, wqkvT, cEX, cEX,
        (size_t)cEX * cEX, (size_t)cQKV * cEX, 0);
    transpose_w<<<dim3(24, 24, cNBLK), 256, 0, stream>>>(kw, wqkvT, cEX, cEX,
        (size_t)cEX * cEX, (size_t)cQKV * cEX, cEX);
    transpose_w<<<dim3(24, 24, cNBLK), 256, 0, stream>>>(vw, wqkvT, cEX, cEX,
        (size_t)cEX * cEX, (size_t)cQKV * cEX, 2 * cEX);
    transpose_w<<<dim3(24, 24, cNBLK), 256, 0, stream>>>(ew, weT, cEX, cEX,
        (size_t)cEX * cEX, (size_t)cEX * cEX, 0);
    transpose_w<<<dim3(96, 24, cNBLK), 256, 0, stream>>>(m1w, wm1T, cEX, 4 * cEX,
        (size_t)cEX * 4 * cEX, (size_t)cEX * 4 * cEX, 0);
    transpose_w<<<dim3(24, 96, cNBLK), 256, 0, stream>>>(m2w, wm2T, 4 * cEX, cEX,
        (size_t)cEX * 4 * cEX, (size_t)cEX * 4 * cEX, 0);
    concat_bias<<<(cNBLK * cQKV + 255) / 256, 256, 0, stream>>>(qbias, kbias, vbias, qkvb);

    embed_kernel<<<cMP, 256, 0, stream>>>(idx, lin_w, lin_b, x);

    for (int blk = 0; blk < cNBLK; ++blk) {
        size_t bo = (size_t)blk * cEX;
        ln_kernel<bf16><<<cMR, 256, 0, stream>>>(x, ln1_s + bo, ln1_b + bo, h);
        // QKV fused: [4096,768] @ [768,2304] -> qkv fp32
        gemm_mfma<4, 4, false, false, false><<<dim3(cQKV / 128, cMP / 128), 256, 0, stream>>>(
            (const short*)h, (const short*)(wqkvT + (size_t)blk * cQKV * cEX),
            qkvb + (size_t)blk * cQKV, nullptr, qkv, cEX, cQKV);
        attn_kernel<<<dim3(16, cNH, cB), 256, 0, stream>>>(qkv, y);
        // e-proj + residual: [4096,768] @ [768,768] + x -> x fp32
        gemm_mfma<2, 4, false, true, false><<<dim3(cEX / 128, cMP / 64), 256, 0, stream>>>(
            (const short*)y, (const short*)(weT + (size_t)blk * cEX * cEX),
            ebias + bo, x, x, cEX, cEX);
        ln_kernel<bf16><<<cMR, 256, 0, stream>>>(x, ln2_s + bo, ln2_b + bo, h2);
        // m1 + relu: [4096,768] @ [768,3072] -> u bf16
        gemm_mfma<4, 4, true, false, true><<<dim3(4 * cEX / 128, cMP / 128), 256, 0, stream>>>(
            (const short*)h2, (const short*)(wm1T + (size_t)blk * cEX * 4 * cEX),
            m1b + (size_t)blk * 4 * cEX, nullptr, u, cEX, 4 * cEX);
        // m2 + residual: [4096,3072] @ [3072,768] + x -> x fp32
        gemm_mfma<2, 4, false, true, false><<<dim3(cEX / 128, cMP / 64), 256, 0, stream>>>(
            (const short*)u, (const short*)(wm2T + (size_t)blk * cEX * 4 * cEX),
            m2b + bo, x, x, 4 * cEX, cEX);
    }
    ln_kernel<float><<<cMR, 256, 0, stream>>>(x, lnf_s, lnf_b, xf);
    head_part_kernel<<<255, 256, 0, stream>>>(xf, head_w, part);
    head_reduce_kernel<<<8, 256, 0, stream>>>(part, head_b, out);
}

// Round 3
// 2447.474 us; speedup vs baseline: 4.7748x; 1.6759x over previous
//
#include <hip/hip_runtime.h>
#include <hip/hip_bf16.h>
#include <math.h>

constexpr int cB = 8, cT = 510, cNH = 12, cEX = 768, cVOC = 256, cNBLK = 11, cHD = 64;
constexpr int cMB = 512;         // padded rows per batch
constexpr int cMP = 4096;        // total padded rows (8*512)
constexpr int cQKV = 3 * cEX;    // 2304

typedef __attribute__((ext_vector_type(8))) short bf16x8;
typedef __attribute__((ext_vector_type(4))) float f32x4;
using bf16 = __hip_bfloat16;

__device__ inline void gload16(const void* g, void* l) {
    __builtin_amdgcn_global_load_lds((const __attribute__((address_space(1))) unsigned int*)g,
                                     (__attribute__((address_space(3))) unsigned int*)l, 16, 0, 0);
}
__device__ inline short f2bs(float f) {
    bf16 b = __float2bfloat16(f);
    return *reinterpret_cast<short*>(&b);
}

// ---------------- embedding: rows b*512+t, zero pads ----------------
__global__ __launch_bounds__(256) void embed_kernel(
    const int* __restrict__ idx, const float* __restrict__ lin_w,
    const float* __restrict__ lin_b, float* __restrict__ x)
{
    int row = blockIdx.x;
    int b = row >> 9, t = row & 511;
    float* xr = x + (size_t)row * cEX;
    if (t >= cT) {
        for (int j = threadIdx.x; j < cEX; j += 256) xr[j] = 0.0f;
        return;
    }
    int tok = idx[b * cT + t] & 1;
    const float* wt = lin_w + (size_t)tok * cEX;
    const float* wp = lin_w + (size_t)(2 + t) * cEX;
    for (int j = threadIdx.x; j < cEX; j += 256) {
        float val = wt[j] + wp[j] + lin_b[j];
        xr[j] = fmaxf(val, 0.0f);
    }
}

// ---------------- layernorm ----------------
template<typename OUT>
__global__ __launch_bounds__(256) void ln_kernel(
    const float* __restrict__ in, const float* __restrict__ s,
    const float* __restrict__ bsh, OUT* __restrict__ out)
{
    int row = blockIdx.x;
    int tid = threadIdx.x;
    const float* xr = in + (size_t)row * cEX;
    float sum = 0.0f, sq = 0.0f;
    for (int j = tid; j < cEX; j += 256) {
        float v = xr[j];
        sum += v; sq += v * v;
    }
    for (int off = 32; off > 0; off >>= 1) {
        sum += __shfl_down(sum, off, 64);
        sq  += __shfl_down(sq, off, 64);
    }
    __shared__ float ssum[4], ssq[4];
    __shared__ float smean, srstd;
    int w = tid >> 6, lane = tid & 63;
    if (lane == 0) { ssum[w] = sum; ssq[w] = sq; }
    __syncthreads();
    if (tid == 0) {
        float S = ssum[0] + ssum[1] + ssum[2] + ssum[3];
        float Q = ssq[0] + ssq[1] + ssq[2] + ssq[3];
        float mean = S * (1.0f / cEX);
        float var = Q * (1.0f / cEX) - mean * mean;
        smean = mean;
        srstd = rsqrtf(var + 1e-5f);
    }
    __syncthreads();
    float mean = smean, rstd = srstd;
    OUT* outr = out + (size_t)row * cEX;
    for (int j = tid; j < cEX; j += 256) {
        float v = (xr[j] - mean) * rstd * s[j] + bsh[j];
        if constexpr (sizeof(OUT) == 2) outr[j] = __float2bfloat16(v);
        else                            outr[j] = v;
    }
}

// ---------------- weight transpose + fp32->bf16: W[K][N] -> WT[N][K] ----------------
__global__ __launch_bounds__(256) void transpose_w(
    const float* __restrict__ W, bf16* __restrict__ WT,
    int K, int N, size_t w_stride, size_t wt_stride, int wt_row_off)
{
    __shared__ float t[32][33];
    const float* Wb = W + (size_t)blockIdx.z * w_stride;
    bf16* WTb = WT + (size_t)blockIdx.z * wt_stride;
    int n0 = blockIdx.x * 32, k0 = blockIdx.y * 32;
    int c = threadIdx.x & 31, ty = threadIdx.x >> 5;
#pragma unroll
    for (int it = 0; it < 4; ++it) {
        int r = ty + it * 8;
        t[r][c] = Wb[(size_t)(k0 + r) * N + n0 + c];
    }
    __syncthreads();
#pragma unroll
    for (int it = 0; it < 4; ++it) {
        int a = ty + it * 8;
        WTb[(size_t)(wt_row_off + n0 + a) * K + k0 + c] = __float2bfloat16(t[c][a]);
    }
}

// ---------------- V transpose: qkv v-section [4096][768] -> vT[768][4096], pads zeroed ----------------
__global__ __launch_bounds__(256) void vtrans_kernel(
    const short* __restrict__ qkv, short* __restrict__ vT)
{
    __shared__ short t[32][33];
    int c0 = blockIdx.x * 32;  // v-col
    int r0 = blockIdx.y * 32;  // row
    int c = threadIdx.x & 31, w = threadIdx.x >> 5;
#pragma unroll
    for (int it = 0; it < 4; ++it) {
        int r = w + it * 8;
        int row = r0 + r;
        bool valid = (row & 511) < cT;
        t[r][c] = valid ? qkv[(size_t)row * cQKV + 2 * cEX + c0 + c] : (short)0;
    }
    __syncthreads();
#pragma unroll
    for (int it = 0; it < 4; ++it) {
        int a = w + it * 8;
        vT[(size_t)(c0 + a) * cMP + r0 + c] = t[c][a];
    }
}

// ---------------- concat q/k/v biases ----------------
__global__ __launch_bounds__(256) void concat_bias(
    const float* __restrict__ qb, const float* __restrict__ kb,
    const float* __restrict__ vb, float* __restrict__ qkvb)
{
    int i = blockIdx.x * 256 + threadIdx.x;
    if (i >= cNBLK * cQKV) return;
    int blk = i / cQKV, c = i - blk * cQKV;
    const float* src; int cc = c;
    if (c < cEX)            { src = qb; }
    else if (c < 2 * cEX)   { src = kb; cc = c - cEX; }
    else                    { src = vb; cc = c - 2 * cEX; }
    qkvb[i] = src[(size_t)blk * cEX + cc];
}

// ---------------- MFMA GEMM (m97 structure, unchanged from round 2) ----------------
template<int FM, int FN, bool RELU, bool RESID, bool OUTBF16>
__global__ __launch_bounds__(256) void gemm_mfma(
    const short* __restrict__ A, const short* __restrict__ BT,
    const float* __restrict__ bias, const float* __restrict__ resid,
    void* __restrict__ Cout, int K, int N)
{
    constexpr int BM = FM * 32, BN = FN * 32;
    __shared__ short ldsA[BM * 32];
    __shared__ short ldsB[BN * 32];
    const int tid = threadIdx.x;
    const int lane = tid & 63, wid = tid >> 6;
    const int wm = wid >> 1, wn = wid & 1;
    const int bm = blockIdx.y * BM, bn = blockIdx.x * BN;

    f32x4 acc[FM][FN];
#pragma unroll
    for (int i = 0; i < FM; ++i)
#pragma unroll
        for (int j = 0; j < FN; ++j)
            acc[i][j] = f32x4{0.f, 0.f, 0.f, 0.f};

    constexpr int CA = BM / 64, CB = BN / 64;
    const int li = lane & 15, gk = lane >> 4;

    for (int k0 = 0; k0 < K; k0 += 32) {
#pragma unroll
        for (int i = 0; i < CA; ++i) {
            int s = i * 256 + tid;
            int r = s >> 2, w = s & 3;
            gload16(A + (size_t)(bm + r) * K + k0 + w * 8,
                    (char*)ldsA + (size_t)(i * 256 + wid * 64) * 16);
        }
#pragma unroll
        for (int i = 0; i < CB; ++i) {
            int s = i * 256 + tid;
            int r = s >> 2, w = s & 3;
            gload16(BT + (size_t)(bn + r) * K + k0 + w * 8,
                    (char*)ldsB + (size_t)(i * 256 + wid * 64) * 16);
        }
        __syncthreads();

        bf16x8 af[FM], bf_[FN];
#pragma unroll
        for (int mi = 0; mi < FM; ++mi)
            af[mi] = *(const bf16x8*)&ldsA[(wm * FM * 16 + mi * 16 + li) * 32 + gk * 8];
#pragma unroll
        for (int ni = 0; ni < FN; ++ni)
            bf_[ni] = *(const bf16x8*)&ldsB[(wn * FN * 16 + ni * 16 + li) * 32 + gk * 8];
#pragma unroll
        for (int mi = 0; mi < FM; ++mi)
#pragma unroll
            for (int ni = 0; ni < FN; ++ni)
                acc[mi][ni] = __builtin_amdgcn_mfma_f32_16x16x32_bf16(
                    af[mi], bf_[ni], acc[mi][ni], 0, 0, 0);
        __syncthreads();
    }

#pragma unroll
    for (int mi = 0; mi < FM; ++mi) {
#pragma unroll
        for (int ni = 0; ni < FN; ++ni) {
            int col = bn + wn * FN * 16 + ni * 16 + li;
            float bv = bias[col];
#pragma unroll
            for (int j = 0; j < 4; ++j) {
                int row = bm + wm * FM * 16 + mi * 16 + gk * 4 + j;
                float v = acc[mi][ni][j] + bv;
                if (RELU) v = fmaxf(v, 0.0f);
                if (RESID) v += resid[(size_t)row * N + col];
                if (OUTBF16)
                    ((bf16*)Cout)[(size_t)row * N + col] = __float2bfloat16(v);
                else
                    ((float*)Cout)[(size_t)row * N + col] = v;
            }
        }
    }
}

// ---------------- MFMA flash attention ----------------
// grid (8 qtiles, 12 heads, 8 batch), 256 thr = 4 waves, wave owns 16 q-rows.
// KV tiles of 32 keys; K/Vt staged via gload16 with pre-swizzled global source.
__global__ __launch_bounds__(256) void attn_mfma(
    const short* __restrict__ qkv, const short* __restrict__ vT, bf16* __restrict__ y)
{
    const int qt = blockIdx.x, h = blockIdx.y, b = blockIdx.z;
    __shared__ short Ks[32 * 64];      // [key][d], chunk-swizzled
    __shared__ short Vs[64 * 32];      // [d][key], chunk-swizzled
    __shared__ short Ss[4][16][40];    // per-wave P (bf16), padded rows
    const int tid = threadIdx.x;
    const int lane = tid & 63, wid = tid >> 6;
    const int li = lane & 15, gk = lane >> 4;

    const size_t rowb = (size_t)b * cMB;
    // Q fragments (held in regs): lane holds q-row (li), d = dh*32 + gk*8 + j
    int qr = qt * 64 + wid * 16 + li;
    int qrc = qr < cT ? qr : cT - 1;
    const short* qrow = qkv + (rowb + qrc) * cQKV + h * cHD;
    bf16x8 qf0 = *(const bf16x8*)(qrow + gk * 8);
    bf16x8 qf1 = *(const bf16x8*)(qrow + 32 + gk * 8);

    f32x4 o[4];
    float mrow[4], lrow[4];
#pragma unroll
    for (int dt = 0; dt < 4; ++dt) o[dt] = f32x4{0.f, 0.f, 0.f, 0.f};
#pragma unroll
    for (int j = 0; j < 4; ++j) { mrow[j] = -3e38f; lrow[j] = 0.f; }

    const int kkey = tid >> 3, kclog = (tid & 7) ^ (kkey & 7);
    const int vd = tid >> 2,  vclog = (tid & 3) ^ (vd & 3);
    const int qloc = qt * 64 + wid * 16 + gk * 4;   // +j = this lane's D rows

    const int nkt = 2 * qt + 2;
    for (int kt = 0; kt < nkt; ++kt) {
        // stage K[32][64]: linear dest, inverse-swizzled source
        gload16(qkv + (rowb + kt * 32 + kkey) * cQKV + cEX + h * cHD + kclog * 8,
                (char*)Ks + wid * 1024);
        // stage Vt[64][32]
        gload16(vT + (size_t)(h * cHD + vd) * cMP + rowb + kt * 32 + vclog * 8,
                (char*)Vs + wid * 1024);
        __syncthreads();

        // QK^T: S[16q x 32keys] as two 16-key subtiles, 2 d-halves each
        f32x4 s0 = f32x4{0.f, 0.f, 0.f, 0.f}, s1 = f32x4{0.f, 0.f, 0.f, 0.f};
        {
            int key0 = li, key1 = 16 + li;
            bf16x8 k00 = *(const bf16x8*)&Ks[key0 * 64 + ((0 + gk) ^ (key0 & 7)) * 8];
            bf16x8 k01 = *(const bf16x8*)&Ks[key0 * 64 + ((4 + gk) ^ (key0 & 7)) * 8];
            bf16x8 k10 = *(const bf16x8*)&Ks[key1 * 64 + ((0 + gk) ^ (key1 & 7)) * 8];
            bf16x8 k11 = *(const bf16x8*)&Ks[key1 * 64 + ((4 + gk) ^ (key1 & 7)) * 8];
            s0 = __builtin_amdgcn_mfma_f32_16x16x32_bf16(qf0, k00, s0, 0, 0, 0);
            s0 = __builtin_amdgcn_mfma_f32_16x16x32_bf16(qf1, k01, s0, 0, 0, 0);
            s1 = __builtin_amdgcn_mfma_f32_16x16x32_bf16(qf0, k10, s1, 0, 0, 0);
            s1 = __builtin_amdgcn_mfma_f32_16x16x32_bf16(qf1, k11, s1, 0, 0, 0);
        }

        // mask + scale
        float sc0[4], sc1[4];
#pragma unroll
        for (int j = 0; j < 4; ++j) {
            int q = qloc + j;
            int key0 = kt * 32 + li, key1 = key0 + 16;
            sc0[j] = (key0 <= q) ? s0[j] * 0.125f : -3e38f;
            sc1[j] = (key1 <= q) ? s1[j] * 0.125f : -3e38f;
        }
        // online softmax (row = j, reduce over 16 lanes li)
        float p0[4], p1[4];
#pragma unroll
        for (int j = 0; j < 4; ++j) {
            float tm = fmaxf(sc0[j], sc1[j]);
            tm = fmaxf(tm, __shfl_xor(tm, 1, 16));
            tm = fmaxf(tm, __shfl_xor(tm, 2, 16));
            tm = fmaxf(tm, __shfl_xor(tm, 4, 16));
            tm = fmaxf(tm, __shfl_xor(tm, 8, 16));
            float mnew = fmaxf(mrow[j], tm);
            p0[j] = __expf(sc0[j] - mnew);
            p1[j] = __expf(sc1[j] - mnew);
            float ps = p0[j] + p1[j];
            ps += __shfl_xor(ps, 1, 16);
            ps += __shfl_xor(ps, 2, 16);
            ps += __shfl_xor(ps, 4, 16);
            ps += __shfl_xor(ps, 8, 16);
            float scale = __expf(mrow[j] - mnew);
            lrow[j] = lrow[j] * scale + ps;
            mrow[j] = mnew;
#pragma unroll
            for (int dt = 0; dt < 4; ++dt) o[dt][j] *= scale;
        }
        // P -> LDS (bf16), wave-private, then PV
#pragma unroll
        for (int j = 0; j < 4; ++j) {
            Ss[wid][gk * 4 + j][li]      = f2bs(p0[j]);
            Ss[wid][gk * 4 + j][16 + li] = f2bs(p1[j]);
        }
        bf16x8 pa = *(const bf16x8*)&Ss[wid][li][gk * 8];
#pragma unroll
        for (int dt = 0; dt < 4; ++dt) {
            int d = dt * 16 + li;
            bf16x8 vf = *(const bf16x8*)&Vs[d * 32 + (gk ^ (d & 3)) * 8];
            o[dt] = __builtin_amdgcn_mfma_f32_16x16x32_bf16(pa, vf, o[dt], 0, 0, 0);
        }
        __syncthreads();
    }

    // epilogue: D rows = qloc+j, cols = dt*16+li
#pragma unroll
    for (int j = 0; j < 4; ++j) {
        int q = qloc + j;
        if (q >= cT) continue;
        float inv = 1.0f / lrow[j];
        bf16* yr = y + (rowb + q) * cEX + h * cHD;
#pragma unroll
        for (int dt = 0; dt < 4; ++dt)
            yr[dt * 16 + li] = __float2bfloat16(o[dt][j] * inv);
    }
}

// ---------------- head ----------------
__global__ __launch_bounds__(256) void head_part_kernel(
    const float* __restrict__ xf, const float* __restrict__ hw, float* __restrict__ part)
{
    __shared__ float xs[8][1536];
    const int tid = threadIdx.x;
    const int k0 = blockIdx.x * 1536;
    // flat offset within batch: (b*512 + t)*768 + e = b*393216 + (t*768+e)
    for (int i = tid; i < 8 * 1536; i += 256) {
        int bb = i / 1536, kk = i - bb * 1536;
        xs[bb][kk] = xf[(size_t)bb * (cMB * cEX) + k0 + kk];
    }
    __syncthreads();
    float acc[8] = {};
    const float* wp = hw + (size_t)k0 * cVOC + tid;
    for (int kk = 0; kk < 1536; ++kk) {
        float w = wp[(size_t)kk * cVOC];
#pragma unroll
        for (int bb = 0; bb < 8; ++bb) acc[bb] += xs[bb][kk] * w;
    }
#pragma unroll
    for (int bb = 0; bb < 8; ++bb)
        part[((size_t)blockIdx.x * 8 + bb) * cVOC + tid] = acc[bb];
}

__global__ __launch_bounds__(256) void head_reduce_kernel(
    const float* __restrict__ part, const float* __restrict__ hb, float* __restrict__ out)
{
    int i = blockIdx.x * 256 + threadIdx.x;
    int bb = i >> 8, vv = i & 255;
    float acc = hb[vv];
    for (int c = 0; c < 255; ++c) acc += part[((size_t)c * 8 + bb) * 256 + vv];
    out[i] = acc;
}

// ---------------- launch ----------------
extern "C" void kernel_launch(void* const* d_in, const int* in_sizes, int n_in,
                              void* d_out, int out_size, void* d_ws, size_t ws_size,
                              hipStream_t stream) {
    (void)in_sizes; (void)n_in; (void)out_size; (void)ws_size;
    const int*   idx    = (const int*)d_in[0];
    const float* lin_w  = (const float*)d_in[1];
    const float* lin_b  = (const float*)d_in[2];
    const float* ln1_s  = (const float*)d_in[3];
    const float* ln1_b  = (const float*)d_in[4];
    const float* qw     = (const float*)d_in[5];
    const float* qbias  = (const float*)d_in[6];
    const float* kw     = (const float*)d_in[7];
    const float* kbias  = (const float*)d_in[8];
    const float* vw     = (const float*)d_in[9];
    const float* vbias  = (const float*)d_in[10];
    const float* ew     = (const float*)d_in[11];
    const float* ebias  = (const float*)d_in[12];
    const float* ln2_s  = (const float*)d_in[13];
    const float* ln2_b  = (const float*)d_in[14];
    const float* m1w    = (const float*)d_in[15];
    const float* m1b    = (const float*)d_in[16];
    const float* m2w    = (const float*)d_in[17];
    const float* m2b    = (const float*)d_in[18];
    const float* lnf_s  = (const float*)d_in[19];
    const float* lnf_b  = (const float*)d_in[20];
    const float* head_w = (const float*)d_in[21];
    const float* head_b = (const float*)d_in[22];
    float* out = (float*)d_out;

    const size_t act = (size_t)cMP * cEX;
    float* x    = (float*)d_ws;                    // [4096][768] fp32
    float* xf   = x + act;                         // [4096][768] fp32
    float* part = xf + act;                        // 255*8*256
    float* qkvb = part + 255 * 8 * 256;            // [11][2304]
    short* qkv  = (short*)(qkvb + cNBLK * cQKV);   // [4096][2304] bf16
    short* vTr  = qkv + (size_t)cMP * cQKV;        // [768][4096] bf16
    short* h    = vTr + (size_t)cEX * cMP;         // [4096][768] bf16
    short* h2   = h + act;
    short* y    = h2 + act;
    short* u    = y + act;                         // [4096][3072] bf16
    short* wqkvT = u + (size_t)cMP * 4 * cEX;      // [11][2304][768]
    short* weT   = wqkvT + (size_t)cNBLK * cQKV * cEX;
    short* wm1T  = weT + (size_t)cNBLK * cEX * cEX;
    short* wm2T  = wm1T + (size_t)cNBLK * cEX * 4 * cEX;

    transpose_w<<<dim3(24, 24, cNBLK), 256, 0, stream>>>(qw, (bf16*)wqkvT, cEX, cEX,
        (size_t)cEX * cEX, (size_t)cQKV * cEX, 0);
    transpose_w<<<dim3(24, 24, cNBLK), 256, 0, stream>>>(kw, (bf16*)wqkvT, cEX, cEX,
        (size_t)cEX * cEX, (size_t)cQKV * cEX, cEX);
    transpose_w<<<dim3(24, 24, cNBLK), 256, 0, stream>>>(vw, (bf16*)wqkvT, cEX, cEX,
        (size_t)cEX * cEX, (size_t)cQKV * cEX, 2 * cEX);
    transpose_w<<<dim3(24, 24, cNBLK), 256, 0, stream>>>(ew, (bf16*)weT, cEX, cEX,
        (size_t)cEX * cEX, (size_t)cEX * cEX, 0);
    transpose_w<<<dim3(96, 24, cNBLK), 256, 0, stream>>>(m1w, (bf16*)wm1T, cEX, 4 * cEX,
        (size_t)cEX * 4 * cEX, (size_t)cEX * 4 * cEX, 0);
    transpose_w<<<dim3(24, 96, cNBLK), 256, 0, stream>>>(m2w, (bf16*)wm2T, 4 * cEX, cEX,
        (size_t)cEX * 4 * cEX, (size_t)cEX * 4 * cEX, 0);
    concat_bias<<<(cNBLK * cQKV + 255) / 256, 256, 0, stream>>>(qbias, kbias, vbias, qkvb);

    embed_kernel<<<cMP, 256, 0, stream>>>(idx, lin_w, lin_b, x);

    for (int blk = 0; blk < cNBLK; ++blk) {
        size_t bo = (size_t)blk * cEX;
        ln_kernel<bf16><<<cMP, 256, 0, stream>>>(x, ln1_s + bo, ln1_b + bo, (bf16*)h);
        gemm_mfma<4, 4, false, false, true><<<dim3(cQKV / 128, cMP / 128), 256, 0, stream>>>(
            h, wqkvT + (size_t)blk * cQKV * cEX, qkvb + (size_t)blk * cQKV, nullptr,
            qkv, cEX, cQKV);
        vtrans_kernel<<<dim3(24, 128), 256, 0, stream>>>(qkv, vTr);
        attn_mfma<<<dim3(8, cNH, cB), 256, 0, stream>>>(qkv, vTr, (bf16*)y);
        gemm_mfma<2, 4, false, true, false><<<dim3(cEX / 128, cMP / 64), 256, 0, stream>>>(
            y, weT + (size_t)blk * cEX * cEX, ebias + bo, x, x, cEX, cEX);
        ln_kernel<bf16><<<cMP, 256, 0, stream>>>(x, ln2_s + bo, ln2_b + bo, (bf16*)h2);
        gemm_mfma<4, 4, true, false, true><<<dim3(4 * cEX / 128, cMP / 128), 256, 0, stream>>>(
            h2, wm1T + (size_t)blk * cEX * 4 * cEX, m1b + (size_t)blk * 4 * cEX, nullptr,
            u, cEX, 4 * cEX);
        gemm_mfma<2, 4, false, true, false><<<dim3(cEX / 128, cMP / 64), 256, 0, stream>>>(
            u, wm2T + (size_t)blk * cEX * 4 * cEX, m2b + bo, x, x, 4 * cEX, cEX);
    }
    ln_kernel<float><<<cMP, 256, 0, stream>>>(x, lnf_s, lnf_b, xf);
    head_part_kernel<<<255, 256, 0, stream>>>(xf, head_w, part);
    head_reduce_kernel<<<8, 256, 0, stream>>>(part, head_b, out);
}

// Round 4
// 2043.090 us; speedup vs baseline: 5.7199x; 1.1979x over previous
//
#include <hip/hip_runtime.h>
#include <hip/hip_bf16.h>
#include <math.h>

constexpr int cB = 8, cT = 510, cNH = 12, cEX = 768, cVOC = 256, cNBLK = 11, cHD = 64;
constexpr int cMB = 512;         // padded rows per batch
constexpr int cMP = 4096;        // total padded rows (8*512)
constexpr int cQKV = 3 * cEX;    // 2304

typedef __attribute__((ext_vector_type(8))) short bf16x8;
typedef __attribute__((ext_vector_type(4))) float f32x4;
using bf16 = __hip_bfloat16;

__device__ inline void gload16(const void* g, void* l) {
    __builtin_amdgcn_global_load_lds((const __attribute__((address_space(1))) unsigned int*)g,
                                     (__attribute__((address_space(3))) unsigned int*)l, 16, 0, 0);
}
__device__ inline short f2bs(float f) {
    bf16 b = __float2bfloat16(f);
    return *reinterpret_cast<short*>(&b);
}

// ---------------- embedding: rows b*512+t, zero pads ----------------
__global__ __launch_bounds__(256) void embed_kernel(
    const int* __restrict__ idx, const float* __restrict__ lin_w,
    const float* __restrict__ lin_b, float* __restrict__ x)
{
    int row = blockIdx.x;
    int b = row >> 9, t = row & 511;
    float* xr = x + (size_t)row * cEX;
    if (t >= cT) {
        for (int j = threadIdx.x; j < cEX; j += 256) xr[j] = 0.0f;
        return;
    }
    int tok = idx[b * cT + t] & 1;
    const float* wt = lin_w + (size_t)tok * cEX;
    const float* wp = lin_w + (size_t)(2 + t) * cEX;
    for (int j = threadIdx.x; j < cEX; j += 256) {
        float val = wt[j] + wp[j] + lin_b[j];
        xr[j] = fmaxf(val, 0.0f);
    }
}

// ---------------- layernorm: one row per wave, no LDS, no block barrier ----------------
template<typename OUT>
__global__ __launch_bounds__(256) void ln_wave(
    const float* __restrict__ in, const float* __restrict__ s,
    const float* __restrict__ bsh, OUT* __restrict__ out)
{
    const int wid = threadIdx.x >> 6, lane = threadIdx.x & 63;
    const int row = blockIdx.x * 4 + wid;
    const float* xr = in + (size_t)row * cEX;
    float4 v[3];
    float sum = 0.f, sq = 0.f;
#pragma unroll
    for (int p = 0; p < 3; ++p) {
        v[p] = *(const float4*)&xr[p * 256 + lane * 4];
        sum += v[p].x + v[p].y + v[p].z + v[p].w;
        sq  += v[p].x * v[p].x + v[p].y * v[p].y + v[p].z * v[p].z + v[p].w * v[p].w;
    }
#pragma unroll
    for (int off = 1; off < 64; off <<= 1) {
        sum += __shfl_xor(sum, off, 64);
        sq  += __shfl_xor(sq, off, 64);
    }
    float mean = sum * (1.0f / cEX);
    float var = sq * (1.0f / cEX) - mean * mean;
    float rstd = rsqrtf(var + 1e-5f);
    OUT* outr = out + (size_t)row * cEX;
#pragma unroll
    for (int p = 0; p < 3; ++p) {
        int c = p * 256 + lane * 4;
        float4 sv = *(const float4*)&s[c];
        float4 bv = *(const float4*)&bsh[c];
        float o0 = (v[p].x - mean) * rstd * sv.x + bv.x;
        float o1 = (v[p].y - mean) * rstd * sv.y + bv.y;
        float o2 = (v[p].z - mean) * rstd * sv.z + bv.z;
        float o3 = (v[p].w - mean) * rstd * sv.w + bv.w;
        if constexpr (sizeof(OUT) == 2) {
            short4 pk;
            pk.x = f2bs(o0); pk.y = f2bs(o1); pk.z = f2bs(o2); pk.w = f2bs(o3);
            *(short4*)&outr[c] = pk;
        } else {
            *(float4*)&outr[c] = make_float4(o0, o1, o2, o3);
        }
    }
}

// ---------------- weight transpose + fp32->bf16: W[K][N] -> WT[N][K] ----------------
__global__ __launch_bounds__(256) void transpose_w(
    const float* __restrict__ W, bf16* __restrict__ WT,
    int K, int N, size_t w_stride, size_t wt_stride, int wt_row_off)
{
    __shared__ float t[32][33];
    const float* Wb = W + (size_t)blockIdx.z * w_stride;
    bf16* WTb = WT + (size_t)blockIdx.z * wt_stride;
    int n0 = blockIdx.x * 32, k0 = blockIdx.y * 32;
    int c = threadIdx.x & 31, ty = threadIdx.x >> 5;
#pragma unroll
    for (int it = 0; it < 4; ++it) {
        int r = ty + it * 8;
        t[r][c] = Wb[(size_t)(k0 + r) * N + n0 + c];
    }
    __syncthreads();
#pragma unroll
    for (int it = 0; it < 4; ++it) {
        int a = ty + it * 8;
        WTb[(size_t)(wt_row_off + n0 + a) * K + k0 + c] = __float2bfloat16(t[c][a]);
    }
}

// ---------------- concat q/k/v biases ----------------
__global__ __launch_bounds__(256) void concat_bias(
    const float* __restrict__ qb, const float* __restrict__ kb,
    const float* __restrict__ vb, float* __restrict__ qkvb)
{
    int i = blockIdx.x * 256 + threadIdx.x;
    if (i >= cNBLK * cQKV) return;
    int blk = i / cQKV, c = i - blk * cQKV;
    const float* src; int cc = c;
    if (c < cEX)            { src = qb; }
    else if (c < 2 * cEX)   { src = kb; cc = c - cEX; }
    else                    { src = vb; cc = c - 2 * cEX; }
    qkvb[i] = src[(size_t)blk * cEX + cc];
}

// ---------------- MFMA GEMM, BK=64 with XOR-swizzled LDS ----------------
// LDS [row][64] bf16 (128B rows = 8x16B chunks). Chunk c of row r holds global
// k-chunk (c ^ (r&7)): linear gload_lds dest + inverse-swizzled global source,
// swizzled ds_read (rule #21). 4 waves 2x2; wave tile (FM*16)x(FN*16).
// VT: columns >= 2*cEX are written transposed to vTr instead of Cout.
template<int FM, int FN, bool RELU, bool RESID, bool OUTBF16, bool VT>
__global__ __launch_bounds__(256) void gemm_mfma(
    const short* __restrict__ A, const short* __restrict__ BT,
    const float* __restrict__ bias, const float* __restrict__ resid,
    void* __restrict__ Cout, short* __restrict__ vTr, int K, int N)
{
    constexpr int BM = FM * 32, BN = FN * 32;
    __shared__ short ldsA[BM * 64];
    __shared__ short ldsB[BN * 64];
    const int tid = threadIdx.x;
    const int lane = tid & 63, wid = tid >> 6;
    const int wm = wid >> 1, wn = wid & 1;
    const int bm = blockIdx.y * BM, bn = blockIdx.x * BN;

    f32x4 acc[FM][FN];
#pragma unroll
    for (int i = 0; i < FM; ++i)
#pragma unroll
        for (int j = 0; j < FN; ++j)
            acc[i][j] = f32x4{0.f, 0.f, 0.f, 0.f};

    constexpr int CA = BM / 32, CB = BN / 32;   // gload16 per thread (8 slots/row)
    const int li = lane & 15, gk = lane >> 4;

    for (int k0 = 0; k0 < K; k0 += 64) {
#pragma unroll
        for (int i = 0; i < CA; ++i) {
            int s = i * 256 + tid;
            int r = s >> 3, c = s & 7;
            gload16(A + (size_t)(bm + r) * K + k0 + (c ^ (r & 7)) * 8,
                    (char*)ldsA + (size_t)(i * 256 + wid * 64) * 16);
        }
#pragma unroll
        for (int i = 0; i < CB; ++i) {
            int s = i * 256 + tid;
            int r = s >> 3, c = s & 7;
            gload16(BT + (size_t)(bn + r) * K + k0 + (c ^ (r & 7)) * 8,
                    (char*)ldsB + (size_t)(i * 256 + wid * 64) * 16);
        }
        __syncthreads();   // compiler drains vmcnt(0) -> LDS ready

        bf16x8 af[FM][2], bf_[FN][2];
#pragma unroll
        for (int mi = 0; mi < FM; ++mi) {
            int row = wm * FM * 16 + mi * 16 + li;
#pragma unroll
            for (int ks = 0; ks < 2; ++ks)
                af[mi][ks] = *(const bf16x8*)&ldsA[row * 64 + ((ks * 4 + gk) ^ (row & 7)) * 8];
        }
#pragma unroll
        for (int ni = 0; ni < FN; ++ni) {
            int row = wn * FN * 16 + ni * 16 + li;
#pragma unroll
            for (int ks = 0; ks < 2; ++ks)
                bf_[ni][ks] = *(const bf16x8*)&ldsB[row * 64 + ((ks * 4 + gk) ^ (row & 7)) * 8];
        }
#pragma unroll
        for (int ks = 0; ks < 2; ++ks)
#pragma unroll
            for (int mi = 0; mi < FM; ++mi)
#pragma unroll
                for (int ni = 0; ni < FN; ++ni)
                    acc[mi][ni] = __builtin_amdgcn_mfma_f32_16x16x32_bf16(
                        af[mi][ks], bf_[ni][ks], acc[mi][ni], 0, 0, 0);
        __syncthreads();   // protect LDS before next stage
    }

    // epilogue: C/D layout col=lane&15, row=(lane>>4)*4+j
#pragma unroll
    for (int mi = 0; mi < FM; ++mi) {
#pragma unroll
        for (int ni = 0; ni < FN; ++ni) {
            int col = bn + wn * FN * 16 + ni * 16 + li;
            float bv = bias[col];
            int row0 = bm + wm * FM * 16 + mi * 16 + gk * 4;
            if (VT && col >= 2 * cEX) {
                // V columns: write transposed (4 consecutive rows per lane = 8B store)
                short4 pk;
                pk.x = f2bs(acc[mi][ni][0] + bv);
                pk.y = f2bs(acc[mi][ni][1] + bv);
                pk.z = f2bs(acc[mi][ni][2] + bv);
                pk.w = f2bs(acc[mi][ni][3] + bv);
                *(short4*)&vTr[(size_t)(col - 2 * cEX) * cMP + row0] = pk;
            } else {
#pragma unroll
                for (int j = 0; j < 4; ++j) {
                    int row = row0 + j;
                    float v = acc[mi][ni][j] + bv;
                    if (RELU) v = fmaxf(v, 0.0f);
                    if (RESID) v += resid[(size_t)row * N + col];
                    if (OUTBF16)
                        ((bf16*)Cout)[(size_t)row * N + col] = __float2bfloat16(v);
                    else
                        ((float*)Cout)[(size_t)row * N + col] = v;
                }
            }
        }
    }
}

// ---------------- MFMA flash attention (unchanged from round 3) ----------------
__global__ __launch_bounds__(256) void attn_mfma(
    const short* __restrict__ qkv, const short* __restrict__ vT, bf16* __restrict__ y)
{
    const int qt = blockIdx.x, h = blockIdx.y, b = blockIdx.z;
    __shared__ short Ks[32 * 64];
    __shared__ short Vs[64 * 32];
    __shared__ short Ss[4][16][40];
    const int tid = threadIdx.x;
    const int lane = tid & 63, wid = tid >> 6;
    const int li = lane & 15, gk = lane >> 4;

    const size_t rowb = (size_t)b * cMB;
    int qr = qt * 64 + wid * 16 + li;
    int qrc = qr < cT ? qr : cT - 1;
    const short* qrow = qkv + (rowb + qrc) * cQKV + h * cHD;
    bf16x8 qf0 = *(const bf16x8*)(qrow + gk * 8);
    bf16x8 qf1 = *(const bf16x8*)(qrow + 32 + gk * 8);

    f32x4 o[4];
    float mrow[4], lrow[4];
#pragma unroll
    for (int dt = 0; dt < 4; ++dt) o[dt] = f32x4{0.f, 0.f, 0.f, 0.f};
#pragma unroll
    for (int j = 0; j < 4; ++j) { mrow[j] = -3e38f; lrow[j] = 0.f; }

    const int kkey = tid >> 3, kclog = (tid & 7) ^ (kkey & 7);
    const int vd = tid >> 2,  vclog = (tid & 3) ^ (vd & 3);
    const int qloc = qt * 64 + wid * 16 + gk * 4;

    const int nkt = 2 * qt + 2;
    for (int kt = 0; kt < nkt; ++kt) {
        gload16(qkv + (rowb + kt * 32 + kkey) * cQKV + cEX + h * cHD + kclog * 8,
                (char*)Ks + wid * 1024);
        gload16(vT + (size_t)(h * cHD + vd) * cMP + rowb + kt * 32 + vclog * 8,
                (char*)Vs + wid * 1024);
        __syncthreads();

        f32x4 s0 = f32x4{0.f, 0.f, 0.f, 0.f}, s1 = f32x4{0.f, 0.f, 0.f, 0.f};
        {
            int key0 = li, key1 = 16 + li;
            bf16x8 k00 = *(const bf16x8*)&Ks[key0 * 64 + ((0 + gk) ^ (key0 & 7)) * 8];
            bf16x8 k01 = *(const bf16x8*)&Ks[key0 * 64 + ((4 + gk) ^ (key0 & 7)) * 8];
            bf16x8 k10 = *(const bf16x8*)&Ks[key1 * 64 + ((0 + gk) ^ (key1 & 7)) * 8];
            bf16x8 k11 = *(const bf16x8*)&Ks[key1 * 64 + ((4 + gk) ^ (key1 & 7)) * 8];
            s0 = __builtin_amdgcn_mfma_f32_16x16x32_bf16(qf0, k00, s0, 0, 0, 0);
            s0 = __builtin_amdgcn_mfma_f32_16x16x32_bf16(qf1, k01, s0, 0, 0, 0);
            s1 = __builtin_amdgcn_mfma_f32_16x16x32_bf16(qf0, k10, s1, 0, 0, 0);
            s1 = __builtin_amdgcn_mfma_f32_16x16x32_bf16(qf1, k11, s1, 0, 0, 0);
        }

        float sc0[4], sc1[4];
#pragma unroll
        for (int j = 0; j < 4; ++j) {
            int q = qloc + j;
            int key0 = kt * 32 + li, key1 = key0 + 16;
            sc0[j] = (key0 <= q) ? s0[j] * 0.125f : -3e38f;
            sc1[j] = (key1 <= q) ? s1[j] * 0.125f : -3e38f;
        }
        float p0[4], p1[4];
#pragma unroll
        for (int j = 0; j < 4; ++j) {
            float tm = fmaxf(sc0[j], sc1[j]);
            tm = fmaxf(tm, __shfl_xor(tm, 1, 16));
            tm = fmaxf(tm, __shfl_xor(tm, 2, 16));
            tm = fmaxf(tm, __shfl_xor(tm, 4, 16));
            tm = fmaxf(tm, __shfl_xor(tm, 8, 16));
            float mnew = fmaxf(mrow[j], tm);
            p0[j] = __expf(sc0[j] - mnew);
            p1[j] = __expf(sc1[j] - mnew);
            float ps = p0[j] + p1[j];
            ps += __shfl_xor(ps, 1, 16);
            ps += __shfl_xor(ps, 2, 16);
            ps += __shfl_xor(ps, 4, 16);
            ps += __shfl_xor(ps, 8, 16);
            float scale = __expf(mrow[j] - mnew);
            lrow[j] = lrow[j] * scale + ps;
            mrow[j] = mnew;
#pragma unroll
            for (int dt = 0; dt < 4; ++dt) o[dt][j] *= scale;
        }
#pragma unroll
        for (int j = 0; j < 4; ++j) {
            Ss[wid][gk * 4 + j][li]      = f2bs(p0[j]);
            Ss[wid][gk * 4 + j][16 + li] = f2bs(p1[j]);
        }
        bf16x8 pa = *(const bf16x8*)&Ss[wid][li][gk * 8];
#pragma unroll
        for (int dt = 0; dt < 4; ++dt) {
            int d = dt * 16 + li;
            bf16x8 vf = *(const bf16x8*)&Vs[d * 32 + (gk ^ (d & 3)) * 8];
            o[dt] = __builtin_amdgcn_mfma_f32_16x16x32_bf16(pa, vf, o[dt], 0, 0, 0);
        }
        __syncthreads();
    }

#pragma unroll
    for (int j = 0; j < 4; ++j) {
        int q = qloc + j;
        if (q >= cT) continue;
        float inv = 1.0f / lrow[j];
        bf16* yr = y + (rowb + q) * cEX + h * cHD;
#pragma unroll
        for (int dt = 0; dt < 4; ++dt)
            yr[dt * 16 + li] = __float2bfloat16(o[dt][j] * inv);
    }
}

// ---------------- head ----------------
__global__ __launch_bounds__(256) void head_part_kernel(
    const float* __restrict__ xf, const float* __restrict__ hw, float* __restrict__ part)
{
    __shared__ float xs[8][1536];
    const int tid = threadIdx.x;
    const int k0 = blockIdx.x * 1536;
    for (int i = tid; i < 8 * 1536; i += 256) {
        int bb = i / 1536, kk = i - bb * 1536;
        xs[bb][kk] = xf[(size_t)bb * (cMB * cEX) + k0 + kk];
    }
    __syncthreads();
    float acc[8] = {};
    const float* wp = hw + (size_t)k0 * cVOC + tid;
    for (int kk = 0; kk < 1536; ++kk) {
        float w = wp[(size_t)kk * cVOC];
#pragma unroll
        for (int bb = 0; bb < 8; ++bb) acc[bb] += xs[bb][kk] * w;
    }
#pragma unroll
    for (int bb = 0; bb < 8; ++bb)
        part[((size_t)blockIdx.x * 8 + bb) * cVOC + tid] = acc[bb];
}

__global__ __launch_bounds__(256) void head_reduce_kernel(
    const float* __restrict__ part, const float* __restrict__ hb, float* __restrict__ out)
{
    int i = blockIdx.x * 256 + threadIdx.x;
    int bb = i >> 8, vv = i & 255;
    float acc = hb[vv];
    for (int c = 0; c < 255; ++c) acc += part[((size_t)c * 8 + bb) * 256 + vv];
    out[i] = acc;
}

// ---------------- launch ----------------
extern "C" void kernel_launch(void* const* d_in, const int* in_sizes, int n_in,
                              void* d_out, int out_size, void* d_ws, size_t ws_size,
                              hipStream_t stream) {
    (void)in_sizes; (void)n_in; (void)out_size; (void)ws_size;
    const int*   idx    = (const int*)d_in[0];
    const float* lin_w  = (const float*)d_in[1];
    const float* lin_b  = (const float*)d_in[2];
    const float* ln1_s  = (const float*)d_in[3];
    const float* ln1_b  = (const float*)d_in[4];
    const float* qw     = (const float*)d_in[5];
    const float* qbias  = (const float*)d_in[6];
    const float* kw     = (const float*)d_in[7];
    const float* kbias  = (const float*)d_in[8];
    const float* vw     = (const float*)d_in[9];
    const float* vbias  = (const float*)d_in[10];
    const float* ew     = (const float*)d_in[11];
    const float* ebias  = (const float*)d_in[12];
    const float* ln2_s  = (const float*)d_in[13];
    const float* ln2_b  = (const float*)d_in[14];
    const float* m1w    = (const float*)d_in[15];
    const float* m1b    = (const float*)d_in[16];
    const float* m2w    = (const float*)d_in[17];
    const float* m2b    = (const float*)d_in[18];
    const float* lnf_s  = (const float*)d_in[19];
    const float* lnf_b  = (const float*)d_in[20];
    const float* head_w = (const float*)d_in[21];
    const float* head_b = (const float*)d_in[22];
    float* out = (float*)d_out;

    const size_t act = (size_t)cMP * cEX;
    float* x    = (float*)d_ws;                    // [4096][768] fp32
    float* xf   = x + act;                         // [4096][768] fp32
    float* part = xf + act;                        // 255*8*256
    float* qkvb = part + 255 * 8 * 256;            // [11][2304]
    short* qkv  = (short*)(qkvb + cNBLK * cQKV);   // [4096][2304] bf16 (V region unused)
    short* vTr  = qkv + (size_t)cMP * cQKV;        // [768][4096] bf16
    short* h    = vTr + (size_t)cEX * cMP;         // [4096][768] bf16
    short* h2   = h + act;
    short* y    = h2 + act;
    short* u    = y + act;                         // [4096][3072] bf16
    short* wqkvT = u + (size_t)cMP * 4 * cEX;      // [11][2304][768]
    short* weT   = wqkvT + (size_t)cNBLK * cQKV * cEX;
    short* wm1T  = weT + (size_t)cNBLK * cEX * cEX;
    short* wm2T  = wm1T + (size_t)cNBLK * cEX * 4 * cEX;

    transpose_w<<<dim3(24, 24, cNBLK), 256, 0, stream>>>(qw, (bf16*)wqkvT, cEX, cEX,
        (size_t)cEX * cEX, (size_t)cQKV * cEX, 0);
    transpose_w<<<dim3(24, 24, cNBLK), 256, 0, stream>>>(kw, (bf16*)wqkvT, cEX, cEX,
        (size_t)cEX * cEX, (size_t)cQKV * cEX, cEX);
    transpose_w<<<dim3(24, 24, cNBLK), 256, 0, stream>>>(vw, (bf16*)wqkvT, cEX, cEX,
        (size_t)cEX * cEX, (size_t)cQKV * cEX, 2 * cEX);
    transpose_w<<<dim3(24, 24, cNBLK), 256, 0, stream>>>(ew, (bf16*)weT, cEX, cEX,
        (size_t)cEX * cEX, (size_t)cEX * cEX, 0);
    transpose_w<<<dim3(96, 24, cNBLK), 256, 0, stream>>>(m1w, (bf16*)wm1T, cEX, 4 * cEX,
        (size_t)cEX * 4 * cEX, (size_t)cEX * 4 * cEX, 0);
    transpose_w<<<dim3(24, 96, cNBLK), 256, 0, stream>>>(m2w, (bf16*)wm2T, 4 * cEX, cEX,
        (size_t)cEX * 4 * cEX, (size_t)cEX * 4 * cEX, 0);
    concat_bias<<<(cNBLK * cQKV + 255) / 256, 256, 0, stream>>>(qbias, kbias, vbias, qkvb);

    embed_kernel<<<cMP, 256, 0, stream>>>(idx, lin_w, lin_b, x);

    for (int blk = 0; blk < cNBLK; ++blk) {
        size_t bo = (size_t)blk * cEX;
        ln_wave<bf16><<<cMP / 4, 256, 0, stream>>>(x, ln1_s + bo, ln1_b + bo, (bf16*)h);
        // QKV fused; V columns written transposed into vTr
        gemm_mfma<4, 4, false, false, true, true><<<dim3(cQKV / 128, cMP / 128), 256, 0, stream>>>(
            h, wqkvT + (size_t)blk * cQKV * cEX, qkvb + (size_t)blk * cQKV, nullptr,
            qkv, vTr, cEX, cQKV);
        attn_mfma<<<dim3(8, cNH, cB), 256, 0, stream>>>(qkv, vTr, (bf16*)y);
        gemm_mfma<2, 4, false, true, false, false><<<dim3(cEX / 128, cMP / 64), 256, 0, stream>>>(
            y, weT + (size_t)blk * cEX * cEX, ebias + bo, x, x, nullptr, cEX, cEX);
        ln_wave<bf16><<<cMP / 4, 256, 0, stream>>>(x, ln2_s + bo, ln2_b + bo, (bf16*)h2);
        gemm_mfma<4, 4, true, false, true, false><<<dim3(4 * cEX / 128, cMP / 128), 256, 0, stream>>>(
            h2, wm1T + (size_t)blk * cEX * 4 * cEX, m1b + (size_t)blk * 4 * cEX, nullptr,
            u, nullptr, cEX, 4 * cEX);
        gemm_mfma<2, 4, false, true, false, false><<<dim3(cEX / 128, cMP / 64), 256, 0, stream>>>(
            u, wm2T + (size_t)blk * cEX * 4 * cEX, m2b + bo, x, x, nullptr, 4 * cEX, cEX);
    }
    ln_wave<float><<<cMP / 4, 256, 0, stream>>>(x, lnf_s, lnf_b, xf);
    head_part_kernel<<<255, 256, 0, stream>>>(xf, head_w, part);
    head_reduce_kernel<<<8, 256, 0, stream>>>(part, head_b, out);
}

// Round 5
// 1888.748 us; speedup vs baseline: 6.1873x; 1.0817x over previous
//
#include <hip/hip_runtime.h>
#include <hip/hip_bf16.h>
#include <math.h>

constexpr int cB = 8, cT = 510, cNH = 12, cEX = 768, cVOC = 256, cNBLK = 11, cHD = 64;
constexpr int cMB = 512;         // padded rows per batch
constexpr int cMP = 4096;        // total padded rows (8*512)
constexpr int cQKV = 3 * cEX;    // 2304

typedef __attribute__((ext_vector_type(8))) short bf16x8;
typedef __attribute__((ext_vector_type(4))) float f32x4;
using bf16 = __hip_bfloat16;

__device__ inline void gload16(const void* g, void* l) {
    __builtin_amdgcn_global_load_lds((const __attribute__((address_space(1))) unsigned int*)g,
                                     (__attribute__((address_space(3))) unsigned int*)l, 16, 0, 0);
}
__device__ inline short f2bs(float f) {
    bf16 b = __float2bfloat16(f);
    return *reinterpret_cast<short*>(&b);
}

// ---------------- embedding: rows b*512+t, zero pads ----------------
__global__ __launch_bounds__(256) void embed_kernel(
    const int* __restrict__ idx, const float* __restrict__ lin_w,
    const float* __restrict__ lin_b, float* __restrict__ x)
{
    int row = blockIdx.x;
    int b = row >> 9, t = row & 511;
    float* xr = x + (size_t)row * cEX;
    if (t >= cT) {
        for (int j = threadIdx.x; j < cEX; j += 256) xr[j] = 0.0f;
        return;
    }
    int tok = idx[b * cT + t] & 1;
    const float* wt = lin_w + (size_t)tok * cEX;
    const float* wp = lin_w + (size_t)(2 + t) * cEX;
    for (int j = threadIdx.x; j < cEX; j += 256) {
        float val = wt[j] + wp[j] + lin_b[j];
        xr[j] = fmaxf(val, 0.0f);
    }
}

// ---------------- layernorm: one row per wave ----------------
template<typename OUT>
__global__ __launch_bounds__(256) void ln_wave(
    const float* __restrict__ in, const float* __restrict__ s,
    const float* __restrict__ bsh, OUT* __restrict__ out)
{
    const int wid = threadIdx.x >> 6, lane = threadIdx.x & 63;
    const int row = blockIdx.x * 4 + wid;
    const float* xr = in + (size_t)row * cEX;
    float4 v[3];
    float sum = 0.f, sq = 0.f;
#pragma unroll
    for (int p = 0; p < 3; ++p) {
        v[p] = *(const float4*)&xr[p * 256 + lane * 4];
        sum += v[p].x + v[p].y + v[p].z + v[p].w;
        sq  += v[p].x * v[p].x + v[p].y * v[p].y + v[p].z * v[p].z + v[p].w * v[p].w;
    }
#pragma unroll
    for (int off = 1; off < 64; off <<= 1) {
        sum += __shfl_xor(sum, off, 64);
        sq  += __shfl_xor(sq, off, 64);
    }
    float mean = sum * (1.0f / cEX);
    float var = sq * (1.0f / cEX) - mean * mean;
    float rstd = rsqrtf(var + 1e-5f);
    OUT* outr = out + (size_t)row * cEX;
#pragma unroll
    for (int p = 0; p < 3; ++p) {
        int c = p * 256 + lane * 4;
        float4 sv = *(const float4*)&s[c];
        float4 bv = *(const float4*)&bsh[c];
        float o0 = (v[p].x - mean) * rstd * sv.x + bv.x;
        float o1 = (v[p].y - mean) * rstd * sv.y + bv.y;
        float o2 = (v[p].z - mean) * rstd * sv.z + bv.z;
        float o3 = (v[p].w - mean) * rstd * sv.w + bv.w;
        if constexpr (sizeof(OUT) == 2) {
            short4 pk;
            pk.x = f2bs(o0); pk.y = f2bs(o1); pk.z = f2bs(o2); pk.w = f2bs(o3);
            *(short4*)&outr[c] = pk;
        } else {
            *(float4*)&outr[c] = make_float4(o0, o1, o2, o3);
        }
    }
}

// ---------------- weight transpose + fp32->bf16: W[K][N] -> WT[N][K] ----------------
__global__ __launch_bounds__(256) void transpose_w(
    const float* __restrict__ W, bf16* __restrict__ WT,
    int K, int N, size_t w_stride, size_t wt_stride, int wt_row_off)
{
    __shared__ float t[32][33];
    const float* Wb = W + (size_t)blockIdx.z * w_stride;
    bf16* WTb = WT + (size_t)blockIdx.z * wt_stride;
    int n0 = blockIdx.x * 32, k0 = blockIdx.y * 32;
    int c = threadIdx.x & 31, ty = threadIdx.x >> 5;
#pragma unroll
    for (int it = 0; it < 4; ++it) {
        int r = ty + it * 8;
        t[r][c] = Wb[(size_t)(k0 + r) * N + n0 + c];
    }
    __syncthreads();
#pragma unroll
    for (int it = 0; it < 4; ++it) {
        int a = ty + it * 8;
        WTb[(size_t)(wt_row_off + n0 + a) * K + k0 + c] = __float2bfloat16(t[c][a]);
    }
}

// ---------------- concat q/k/v biases ----------------
__global__ __launch_bounds__(256) void concat_bias(
    const float* __restrict__ qb, const float* __restrict__ kb,
    const float* __restrict__ vb, float* __restrict__ qkvb)
{
    int i = blockIdx.x * 256 + threadIdx.x;
    if (i >= cNBLK * cQKV) return;
    int blk = i / cQKV, c = i - blk * cQKV;
    const float* src; int cc = c;
    if (c < cEX)            { src = qb; }
    else if (c < 2 * cEX)   { src = kb; cc = c - cEX; }
    else                    { src = vb; cc = c - 2 * cEX; }
    qkvb[i] = src[(size_t)blk * cEX + cc];
}

// ---------------- MFMA GEMM: BK=64, double-buffered LDS, counted vmcnt ----------------
// T2 XOR swizzle (chunk c of row r holds global chunk c^(r&7); gload_lds linear dest,
// inverse-swizzled source, swizzled ds_read). T4: raw s_barrier + counted vmcnt keeps
// next-tile stage in flight across the barrier. T5: setprio around MFMA cluster.
// 4 waves 2x2; wave tile (FM*16)x(FN*16)*... per-wave (FM*16)x(FN*16) fragments of 16.
// VT: columns >= 2*cEX written transposed to vTr (QKV path).
template<int FM, int FN, bool RELU, bool RESID, bool OUTBF16, bool VT>
__global__ __launch_bounds__(256) void gemm_db(
    const short* __restrict__ A, const short* __restrict__ BT,
    const float* __restrict__ bias, const float* __restrict__ resid,
    void* __restrict__ Cout, short* __restrict__ vTr, int K, int N)
{
    constexpr int BM = FM * 32, BN = FN * 32;
    constexpr int TS = (BM + BN) * 64;          // shorts per K-tile buffer
    constexpr int CA = BM / 32, CB = BN / 32;   // gload16 per thread for A / B
    constexpr int LPT = CA + CB;                // loads per thread per K-tile
    __shared__ short lds[2 * TS];
    const int tid = threadIdx.x;
    const int lane = tid & 63, wid = tid >> 6;
    const int wm = wid >> 1, wn = wid & 1;
    const int bm = blockIdx.y * BM, bn = blockIdx.x * BN;
    const int li = lane & 15, gk = lane >> 4;

    f32x4 acc[FM][FN];
#pragma unroll
    for (int i = 0; i < FM; ++i)
#pragma unroll
        for (int j = 0; j < FN; ++j)
            acc[i][j] = f32x4{0.f, 0.f, 0.f, 0.f};

    auto stage = [&](int kt, int buf) {
        short* la = &lds[buf * TS];
        short* lb = la + BM * 64;
#pragma unroll
        for (int i = 0; i < CA; ++i) {
            int s = i * 256 + tid;
            int r = s >> 3, c = s & 7;
            gload16(A + (size_t)(bm + r) * K + kt * 64 + (c ^ (r & 7)) * 8,
                    (char*)la + (size_t)(i * 256 + wid * 64) * 16);
        }
#pragma unroll
        for (int i = 0; i < CB; ++i) {
            int s = i * 256 + tid;
            int r = s >> 3, c = s & 7;
            gload16(BT + (size_t)(bn + r) * K + kt * 64 + (c ^ (r & 7)) * 8,
                    (char*)lb + (size_t)(i * 256 + wid * 64) * 16);
        }
    };

    const int nkt = K >> 6;
    stage(0, 0);
    stage(1, 1);

    for (int t = 0; t < nkt; ++t) {
        // wait for tile t only; tile t+1's LPT loads stay in flight
        if (t + 1 < nkt) {
            if constexpr (LPT == 8) asm volatile("s_waitcnt vmcnt(8)" ::: "memory");
            else                    asm volatile("s_waitcnt vmcnt(6)" ::: "memory");
        } else {
            asm volatile("s_waitcnt vmcnt(0)" ::: "memory");
        }
        __builtin_amdgcn_s_barrier();

        const short* la = &lds[(t & 1) * TS];
        const short* lb = la + BM * 64;
        bf16x8 af[FM][2], bf_[FN][2];
#pragma unroll
        for (int mi = 0; mi < FM; ++mi) {
            int row = wm * FM * 16 + mi * 16 + li;
#pragma unroll
            for (int ks = 0; ks < 2; ++ks)
                af[mi][ks] = *(const bf16x8*)&la[row * 64 + ((ks * 4 + gk) ^ (row & 7)) * 8];
        }
#pragma unroll
        for (int ni = 0; ni < FN; ++ni) {
            int row = wn * FN * 16 + ni * 16 + li;
#pragma unroll
            for (int ks = 0; ks < 2; ++ks)
                bf_[ni][ks] = *(const bf16x8*)&lb[row * 64 + ((ks * 4 + gk) ^ (row & 7)) * 8];
        }
        __builtin_amdgcn_s_setprio(1);
#pragma unroll
        for (int ks = 0; ks < 2; ++ks)
#pragma unroll
            for (int mi = 0; mi < FM; ++mi)
#pragma unroll
                for (int ni = 0; ni < FN; ++ni)
                    acc[mi][ni] = __builtin_amdgcn_mfma_f32_16x16x32_bf16(
                        af[mi][ks], bf_[ni][ks], acc[mi][ni], 0, 0, 0);
        __builtin_amdgcn_s_setprio(0);

        asm volatile("" ::: "memory");      // fence: ds_reads stay before barrier
        __builtin_amdgcn_s_barrier();       // all waves done reading buf[t&1]
        if (t + 2 < nkt) stage(t + 2, t & 1);
    }

    // epilogue: C/D layout col=lane&15, row=(lane>>4)*4+j
#pragma unroll
    for (int mi = 0; mi < FM; ++mi) {
#pragma unroll
        for (int ni = 0; ni < FN; ++ni) {
            int col = bn + wn * FN * 16 + ni * 16 + li;
            float bv = bias[col];
            int row0 = bm + wm * FM * 16 + mi * 16 + gk * 4;
            if (VT && col >= 2 * cEX) {
                short4 pk;
                pk.x = f2bs(acc[mi][ni][0] + bv);
                pk.y = f2bs(acc[mi][ni][1] + bv);
                pk.z = f2bs(acc[mi][ni][2] + bv);
                pk.w = f2bs(acc[mi][ni][3] + bv);
                *(short4*)&vTr[(size_t)(col - 2 * cEX) * cMP + row0] = pk;
            } else {
#pragma unroll
                for (int j = 0; j < 4; ++j) {
                    int row = row0 + j;
                    float v = acc[mi][ni][j] + bv;
                    if (RELU) v = fmaxf(v, 0.0f);
                    if (RESID) v += resid[(size_t)row * N + col];
                    if (OUTBF16)
                        ((bf16*)Cout)[(size_t)row * N + col] = __float2bfloat16(v);
                    else
                        ((float*)Cout)[(size_t)row * N + col] = v;
                }
            }
        }
    }
}

// ---------------- MFMA flash attention (unchanged) ----------------
__global__ __launch_bounds__(256) void attn_mfma(
    const short* __restrict__ qkv, const short* __restrict__ vT, bf16* __restrict__ y)
{
    const int qt = blockIdx.x, h = blockIdx.y, b = blockIdx.z;
    __shared__ short Ks[32 * 64];
    __shared__ short Vs[64 * 32];
    __shared__ short Ss[4][16][40];
    const int tid = threadIdx.x;
    const int lane = tid & 63, wid = tid >> 6;
    const int li = lane & 15, gk = lane >> 4;

    const size_t rowb = (size_t)b * cMB;
    int qr = qt * 64 + wid * 16 + li;
    int qrc = qr < cT ? qr : cT - 1;
    const short* qrow = qkv + (rowb + qrc) * cQKV + h * cHD;
    bf16x8 qf0 = *(const bf16x8*)(qrow + gk * 8);
    bf16x8 qf1 = *(const bf16x8*)(qrow + 32 + gk * 8);

    f32x4 o[4];
    float mrow[4], lrow[4];
#pragma unroll
    for (int dt = 0; dt < 4; ++dt) o[dt] = f32x4{0.f, 0.f, 0.f, 0.f};
#pragma unroll
    for (int j = 0; j < 4; ++j) { mrow[j] = -3e38f; lrow[j] = 0.f; }

    const int kkey = tid >> 3, kclog = (tid & 7) ^ (kkey & 7);
    const int vd = tid >> 2,  vclog = (tid & 3) ^ (vd & 3);
    const int qloc = qt * 64 + wid * 16 + gk * 4;

    const int nkt = 2 * qt + 2;
    for (int kt = 0; kt < nkt; ++kt) {
        gload16(qkv + (rowb + kt * 32 + kkey) * cQKV + cEX + h * cHD + kclog * 8,
                (char*)Ks + wid * 1024);
        gload16(vT + (size_t)(h * cHD + vd) * cMP + rowb + kt * 32 + vclog * 8,
                (char*)Vs + wid * 1024);
        __syncthreads();

        f32x4 s0 = f32x4{0.f, 0.f, 0.f, 0.f}, s1 = f32x4{0.f, 0.f, 0.f, 0.f};
        {
            int key0 = li, key1 = 16 + li;
            bf16x8 k00 = *(const bf16x8*)&Ks[key0 * 64 + ((0 + gk) ^ (key0 & 7)) * 8];
            bf16x8 k01 = *(const bf16x8*)&Ks[key0 * 64 + ((4 + gk) ^ (key0 & 7)) * 8];
            bf16x8 k10 = *(const bf16x8*)&Ks[key1 * 64 + ((0 + gk) ^ (key1 & 7)) * 8];
            bf16x8 k11 = *(const bf16x8*)&Ks[key1 * 64 + ((4 + gk) ^ (key1 & 7)) * 8];
            s0 = __builtin_amdgcn_mfma_f32_16x16x32_bf16(qf0, k00, s0, 0, 0, 0);
            s0 = __builtin_amdgcn_mfma_f32_16x16x32_bf16(qf1, k01, s0, 0, 0, 0);
            s1 = __builtin_amdgcn_mfma_f32_16x16x32_bf16(qf0, k10, s1, 0, 0, 0);
            s1 = __builtin_amdgcn_mfma_f32_16x16x32_bf16(qf1, k11, s1, 0, 0, 0);
        }

        float sc0[4], sc1[4];
#pragma unroll
        for (int j = 0; j < 4; ++j) {
            int q = qloc + j;
            int key0 = kt * 32 + li, key1 = key0 + 16;
            sc0[j] = (key0 <= q) ? s0[j] * 0.125f : -3e38f;
            sc1[j] = (key1 <= q) ? s1[j] * 0.125f : -3e38f;
        }
        float p0[4], p1[4];
#pragma unroll
        for (int j = 0; j < 4; ++j) {
            float tm = fmaxf(sc0[j], sc1[j]);
            tm = fmaxf(tm, __shfl_xor(tm, 1, 16));
            tm = fmaxf(tm, __shfl_xor(tm, 2, 16));
            tm = fmaxf(tm, __shfl_xor(tm, 4, 16));
            tm = fmaxf(tm, __shfl_xor(tm, 8, 16));
            float mnew = fmaxf(mrow[j], tm);
            p0[j] = __expf(sc0[j] - mnew);
            p1[j] = __expf(sc1[j] - mnew);
            float ps = p0[j] + p1[j];
            ps += __shfl_xor(ps, 1, 16);
            ps += __shfl_xor(ps, 2, 16);
            ps += __shfl_xor(ps, 4, 16);
            ps += __shfl_xor(ps, 8, 16);
            float scale = __expf(mrow[j] - mnew);
            lrow[j] = lrow[j] * scale + ps;
            mrow[j] = mnew;
#pragma unroll
            for (int dt = 0; dt < 4; ++dt) o[dt][j] *= scale;
        }
#pragma unroll
        for (int j = 0; j < 4; ++j) {
            Ss[wid][gk * 4 + j][li]      = f2bs(p0[j]);
            Ss[wid][gk * 4 + j][16 + li] = f2bs(p1[j]);
        }
        bf16x8 pa = *(const bf16x8*)&Ss[wid][li][gk * 8];
#pragma unroll
        for (int dt = 0; dt < 4; ++dt) {
            int d = dt * 16 + li;
            bf16x8 vf = *(const bf16x8*)&Vs[d * 32 + (gk ^ (d & 3)) * 8];
            o[dt] = __builtin_amdgcn_mfma_f32_16x16x32_bf16(pa, vf, o[dt], 0, 0, 0);
        }
        __syncthreads();
    }

#pragma unroll
    for (int j = 0; j < 4; ++j) {
        int q = qloc + j;
        if (q >= cT) continue;
        float inv = 1.0f / lrow[j];
        bf16* yr = y + (rowb + q) * cEX + h * cHD;
#pragma unroll
        for (int dt = 0; dt < 4; ++dt)
            yr[dt * 16 + li] = __float2bfloat16(o[dt][j] * inv);
    }
}

// ---------------- head ----------------
__global__ __launch_bounds__(256) void head_part_kernel(
    const float* __restrict__ xf, const float* __restrict__ hw, float* __restrict__ part)
{
    __shared__ float xs[8][1536];
    const int tid = threadIdx.x;
    const int k0 = blockIdx.x * 1536;
    for (int i = tid; i < 8 * 1536; i += 256) {
        int bb = i / 1536, kk = i - bb * 1536;
        xs[bb][kk] = xf[(size_t)bb * (cMB * cEX) + k0 + kk];
    }
    __syncthreads();
    float acc[8] = {};
    const float* wp = hw + (size_t)k0 * cVOC + tid;
    for (int kk = 0; kk < 1536; ++kk) {
        float w = wp[(size_t)kk * cVOC];
#pragma unroll
        for (int bb = 0; bb < 8; ++bb) acc[bb] += xs[bb][kk] * w;
    }
#pragma unroll
    for (int bb = 0; bb < 8; ++bb)
        part[((size_t)blockIdx.x * 8 + bb) * cVOC + tid] = acc[bb];
}

__global__ __launch_bounds__(256) void head_reduce_kernel(
    const float* __restrict__ part, const float* __restrict__ hb, float* __restrict__ out)
{
    int i = blockIdx.x * 256 + threadIdx.x;
    int bb = i >> 8, vv = i & 255;
    float acc = hb[vv];
    for (int c = 0; c < 255; ++c) acc += part[((size_t)c * 8 + bb) * 256 + vv];
    out[i] = acc;
}

// ---------------- launch ----------------
extern "C" void kernel_launch(void* const* d_in, const int* in_sizes, int n_in,
                              void* d_out, int out_size, void* d_ws, size_t ws_size,
                              hipStream_t stream) {
    (void)in_sizes; (void)n_in; (void)out_size; (void)ws_size;
    const int*   idx    = (const int*)d_in[0];
    const float* lin_w  = (const float*)d_in[1];
    const float* lin_b  = (const float*)d_in[2];
    const float* ln1_s  = (const float*)d_in[3];
    const float* ln1_b  = (const float*)d_in[4];
    const float* qw     = (const float*)d_in[5];
    const float* qbias  = (const float*)d_in[6];
    const float* kw     = (const float*)d_in[7];
    const float* kbias  = (const float*)d_in[8];
    const float* vw     = (const float*)d_in[9];
    const float* vbias  = (const float*)d_in[10];
    const float* ew     = (const float*)d_in[11];
    const float* ebias  = (const float*)d_in[12];
    const float* ln2_s  = (const float*)d_in[13];
    const float* ln2_b  = (const float*)d_in[14];
    const float* m1w    = (const float*)d_in[15];
    const float* m1b    = (const float*)d_in[16];
    const float* m2w    = (const float*)d_in[17];
    const float* m2b    = (const float*)d_in[18];
    const float* lnf_s  = (const float*)d_in[19];
    const float* lnf_b  = (const float*)d_in[20];
    const float* head_w = (const float*)d_in[21];
    const float* head_b = (const float*)d_in[22];
    float* out = (float*)d_out;

    const size_t act = (size_t)cMP * cEX;
    float* x    = (float*)d_ws;                    // [4096][768] fp32
    float* xf   = x + act;                         // [4096][768] fp32
    float* part = xf + act;                        // 255*8*256
    float* qkvb = part + 255 * 8 * 256;            // [11][2304]
    short* qkv  = (short*)(qkvb + cNBLK * cQKV);   // [4096][2304] bf16 (V region unused)
    short* vTr  = qkv + (size_t)cMP * cQKV;        // [768][4096] bf16
    short* h    = vTr + (size_t)cEX * cMP;         // [4096][768] bf16
    short* h2   = h + act;
    short* y    = h2 + act;
    short* u    = y + act;                         // [4096][3072] bf16
    short* wqkvT = u + (size_t)cMP * 4 * cEX;      // [11][2304][768]
    short* weT   = wqkvT + (size_t)cNBLK * cQKV * cEX;
    short* wm1T  = weT + (size_t)cNBLK * cEX * cEX;
    short* wm2T  = wm1T + (size_t)cNBLK * cEX * 4 * cEX;

    transpose_w<<<dim3(24, 24, cNBLK), 256, 0, stream>>>(qw, (bf16*)wqkvT, cEX, cEX,
        (size_t)cEX * cEX, (size_t)cQKV * cEX, 0);
    transpose_w<<<dim3(24, 24, cNBLK), 256, 0, stream>>>(kw, (bf16*)wqkvT, cEX, cEX,
        (size_t)cEX * cEX, (size_t)cQKV * cEX, cEX);
    transpose_w<<<dim3(24, 24, cNBLK), 256, 0, stream>>>(vw, (bf16*)wqkvT, cEX, cEX,
        (size_t)cEX * cEX, (size_t)cQKV * cEX, 2 * cEX);
    transpose_w<<<dim3(24, 24, cNBLK), 256, 0, stream>>>(ew, (bf16*)weT, cEX, cEX,
        (size_t)cEX * cEX, (size_t)cEX * cEX, 0);
    transpose_w<<<dim3(96, 24, cNBLK), 256, 0, stream>>>(m1w, (bf16*)wm1T, cEX, 4 * cEX,
        (size_t)cEX * 4 * cEX, (size_t)cEX * 4 * cEX, 0);
    transpose_w<<<dim3(24, 96, cNBLK), 256, 0, stream>>>(m2w, (bf16*)wm2T, 4 * cEX, cEX,
        (size_t)cEX * 4 * cEX, (size_t)cEX * 4 * cEX, 0);
    concat_bias<<<(cNBLK * cQKV + 255) / 256, 256, 0, stream>>>(qbias, kbias, vbias, qkvb);

    embed_kernel<<<cMP, 256, 0, stream>>>(idx, lin_w, lin_b, x);

    for (int blk = 0; blk < cNBLK; ++blk) {
        size_t bo = (size_t)blk * cEX;
        ln_wave<bf16><<<cMP / 4, 256, 0, stream>>>(x, ln1_s + bo, ln1_b + bo, (bf16*)h);
        // QKV fused; V columns written transposed into vTr
        gemm_db<4, 4, false, false, true, true><<<dim3(cQKV / 128, cMP / 128), 256, 0, stream>>>(
            h, wqkvT + (size_t)blk * cQKV * cEX, qkvb + (size_t)blk * cQKV, nullptr,
            qkv, vTr, cEX, cQKV);
        attn_mfma<<<dim3(8, cNH, cB), 256, 0, stream>>>(qkv, vTr, (bf16*)y);
        gemm_db<2, 4, false, true, false, false><<<dim3(cEX / 128, cMP / 64), 256, 0, stream>>>(
            y, weT + (size_t)blk * cEX * cEX, ebias + bo, x, x, nullptr, cEX, cEX);
        ln_wave<bf16><<<cMP / 4, 256, 0, stream>>>(x, ln2_s + bo, ln2_b + bo, (bf16*)h2);
        gemm_db<4, 4, true, false, true, false><<<dim3(4 * cEX / 128, cMP / 128), 256, 0, stream>>>(
            h2, wm1T + (size_t)blk * cEX * 4 * cEX, m1b + (size_t)blk * 4 * cEX, nullptr,
            u, nullptr, cEX, 4 * cEX);
        gemm_db<2, 4, false, true, false, false><<<dim3(cEX / 128, cMP / 64), 256, 0, stream>>>(
            u, wm2T + (size_t)blk * cEX * 4 * cEX, m2b + bo, x, x, nullptr, 4 * cEX, cEX);
    }
    ln_wave<float><<<cMP / 4, 256, 0, stream>>>(x, lnf_s, lnf_b, xf);
    head_part_kernel<<<255, 256, 0, stream>>>(xf, head_w, part);
    head_reduce_kernel<<<8, 256, 0, stream>>>(part, head_b, out);
}

// Round 6
// 1794.344 us; speedup vs baseline: 6.5128x; 1.0526x over previous
//
#include <hip/hip_runtime.h>
#include <hip/hip_bf16.h>
#include <math.h>

constexpr int cB = 8, cT = 510, cNH = 12, cEX = 768, cVOC = 256, cNBLK = 11, cHD = 64;
constexpr int cMB = 512;         // padded rows per batch
constexpr int cMP = 4096;        // total padded rows (8*512)
constexpr int cQKV = 3 * cEX;    // 2304

typedef __attribute__((ext_vector_type(8))) short bf16x8;
typedef __attribute__((ext_vector_type(4))) float f32x4;
using bf16 = __hip_bfloat16;

__device__ inline void gload16(const void* g, void* l) {
    __builtin_amdgcn_global_load_lds((const __attribute__((address_space(1))) unsigned int*)g,
                                     (__attribute__((address_space(3))) unsigned int*)l, 16, 0, 0);
}
__device__ inline short f2bs(float f) {
    bf16 b = __float2bfloat16(f);
    return *reinterpret_cast<short*>(&b);
}

// ---------------- embedding: rows b*512+t, zero pads ----------------
__global__ __launch_bounds__(256) void embed_kernel(
    const int* __restrict__ idx, const float* __restrict__ lin_w,
    const float* __restrict__ lin_b, float* __restrict__ x)
{
    int row = blockIdx.x;
    int b = row >> 9, t = row & 511;
    float* xr = x + (size_t)row * cEX;
    if (t >= cT) {
        for (int j = threadIdx.x; j < cEX; j += 256) xr[j] = 0.0f;
        return;
    }
    int tok = idx[b * cT + t] & 1;
    const float* wt = lin_w + (size_t)tok * cEX;
    const float* wp = lin_w + (size_t)(2 + t) * cEX;
    for (int j = threadIdx.x; j < cEX; j += 256) {
        float val = wt[j] + wp[j] + lin_b[j];
        xr[j] = fmaxf(val, 0.0f);
    }
}

// ---------------- layernorm: one row per wave ----------------
template<typename OUT>
__global__ __launch_bounds__(256) void ln_wave(
    const float* __restrict__ in, const float* __restrict__ s,
    const float* __restrict__ bsh, OUT* __restrict__ out)
{
    const int wid = threadIdx.x >> 6, lane = threadIdx.x & 63;
    const int row = blockIdx.x * 4 + wid;
    const float* xr = in + (size_t)row * cEX;
    float4 v[3];
    float sum = 0.f, sq = 0.f;
#pragma unroll
    for (int p = 0; p < 3; ++p) {
        v[p] = *(const float4*)&xr[p * 256 + lane * 4];
        sum += v[p].x + v[p].y + v[p].z + v[p].w;
        sq  += v[p].x * v[p].x + v[p].y * v[p].y + v[p].z * v[p].z + v[p].w * v[p].w;
    }
#pragma unroll
    for (int off = 1; off < 64; off <<= 1) {
        sum += __shfl_xor(sum, off, 64);
        sq  += __shfl_xor(sq, off, 64);
    }
    float mean = sum * (1.0f / cEX);
    float var = sq * (1.0f / cEX) - mean * mean;
    float rstd = rsqrtf(var + 1e-5f);
    OUT* outr = out + (size_t)row * cEX;
#pragma unroll
    for (int p = 0; p < 3; ++p) {
        int c = p * 256 + lane * 4;
        float4 sv = *(const float4*)&s[c];
        float4 bv = *(const float4*)&bsh[c];
        float o0 = (v[p].x - mean) * rstd * sv.x + bv.x;
        float o1 = (v[p].y - mean) * rstd * sv.y + bv.y;
        float o2 = (v[p].z - mean) * rstd * sv.z + bv.z;
        float o3 = (v[p].w - mean) * rstd * sv.w + bv.w;
        if constexpr (sizeof(OUT) == 2) {
            short4 pk;
            pk.x = f2bs(o0); pk.y = f2bs(o1); pk.z = f2bs(o2); pk.w = f2bs(o3);
            *(short4*)&outr[c] = pk;
        } else {
            *(float4*)&outr[c] = make_float4(o0, o1, o2, o3);
        }
    }
}

// ---------------- weight transpose + fp32->bf16: W[K][N] -> WT[N][K] ----------------
__global__ __launch_bounds__(256) void transpose_w(
    const float* __restrict__ W, bf16* __restrict__ WT,
    int K, int N, size_t w_stride, size_t wt_stride, int wt_row_off)
{
    __shared__ float t[32][33];
    const float* Wb = W + (size_t)blockIdx.z * w_stride;
    bf16* WTb = WT + (size_t)blockIdx.z * wt_stride;
    int n0 = blockIdx.x * 32, k0 = blockIdx.y * 32;
    int c = threadIdx.x & 31, ty = threadIdx.x >> 5;
#pragma unroll
    for (int it = 0; it < 4; ++it) {
        int r = ty + it * 8;
        t[r][c] = Wb[(size_t)(k0 + r) * N + n0 + c];
    }
    __syncthreads();
#pragma unroll
    for (int it = 0; it < 4; ++it) {
        int a = ty + it * 8;
        WTb[(size_t)(wt_row_off + n0 + a) * K + k0 + c] = __float2bfloat16(t[c][a]);
    }
}

// ---------------- concat q/k/v biases ----------------
__global__ __launch_bounds__(256) void concat_bias(
    const float* __restrict__ qb, const float* __restrict__ kb,
    const float* __restrict__ vb, float* __restrict__ qkvb)
{
    int i = blockIdx.x * 256 + threadIdx.x;
    if (i >= cNBLK * cQKV) return;
    int blk = i / cQKV, c = i - blk * cQKV;
    const float* src; int cc = c;
    if (c < cEX)            { src = qb; }
    else if (c < 2 * cEX)   { src = kb; cc = c - cEX; }
    else                    { src = vb; cc = c - 2 * cEX; }
    qkvb[i] = src[(size_t)blk * cEX + cc];
}

// ---------------- MFMA GEMM: BK=64, dbuf, counted vmcnt, ks-phase split ----------------
// Phase P1: ds_read ks0 frags -> MFMA ks0 (ks1 reads may overlap the cluster).
// Phase P2: ds_read ks1 frags -> lgkmcnt(0) -> barrier -> stage(t+2) (overlaps MFMA ks1).
template<int FM, int FN, bool RELU, bool RESID, bool OUTBF16, bool VT>
__global__ __launch_bounds__(256) void gemm_db(
    const short* __restrict__ A, const short* __restrict__ BT,
    const float* __restrict__ bias, const float* __restrict__ resid,
    void* __restrict__ Cout, short* __restrict__ vTr, int K, int N)
{
    constexpr int BM = FM * 32, BN = FN * 32;
    constexpr int TS = (BM + BN) * 64;          // shorts per K-tile buffer
    constexpr int CA = BM / 32, CB = BN / 32;   // gload16 per thread for A / B
    constexpr int LPT = CA + CB;                // loads per thread per K-tile
    __shared__ short lds[2 * TS];
    const int tid = threadIdx.x;
    const int lane = tid & 63, wid = tid >> 6;
    const int wm = wid >> 1, wn = wid & 1;
    const int bm = blockIdx.y * BM, bn = blockIdx.x * BN;
    const int li = lane & 15, gk = lane >> 4;

    f32x4 acc[FM][FN];
#pragma unroll
    for (int i = 0; i < FM; ++i)
#pragma unroll
        for (int j = 0; j < FN; ++j)
            acc[i][j] = f32x4{0.f, 0.f, 0.f, 0.f};

    auto stage = [&](int kt, int buf) {
        short* la = &lds[buf * TS];
        short* lb = la + BM * 64;
#pragma unroll
        for (int i = 0; i < CA; ++i) {
            int s = i * 256 + tid;
            int r = s >> 3, c = s & 7;
            gload16(A + (size_t)(bm + r) * K + kt * 64 + (c ^ (r & 7)) * 8,
                    (char*)la + (size_t)(i * 256 + wid * 64) * 16);
        }
#pragma unroll
        for (int i = 0; i < CB; ++i) {
            int s = i * 256 + tid;
            int r = s >> 3, c = s & 7;
            gload16(BT + (size_t)(bn + r) * K + kt * 64 + (c ^ (r & 7)) * 8,
                    (char*)lb + (size_t)(i * 256 + wid * 64) * 16);
        }
    };

    const int nkt = K >> 6;
    stage(0, 0);
    stage(1, 1);

    for (int t = 0; t < nkt; ++t) {
        // wait for tile t only; tile t+1's LPT loads stay in flight
        if (t + 1 < nkt) {
            if constexpr (LPT == 8) asm volatile("s_waitcnt vmcnt(8)" ::: "memory");
            else                    asm volatile("s_waitcnt vmcnt(6)" ::: "memory");
        } else {
            asm volatile("s_waitcnt vmcnt(0)" ::: "memory");
        }
        __builtin_amdgcn_s_barrier();

        const short* la = &lds[(t & 1) * TS];
        const short* lb = la + BM * 64;

        // ---- phase 1: ks0 ----
        bf16x8 af0[FM], bf0[FN];
#pragma unroll
        for (int mi = 0; mi < FM; ++mi) {
            int row = wm * FM * 16 + mi * 16 + li;
            af0[mi] = *(const bf16x8*)&la[row * 64 + (gk ^ (row & 7)) * 8];
        }
#pragma unroll
        for (int ni = 0; ni < FN; ++ni) {
            int row = wn * FN * 16 + ni * 16 + li;
            bf0[ni] = *(const bf16x8*)&lb[row * 64 + (gk ^ (row & 7)) * 8];
        }
        __builtin_amdgcn_s_setprio(1);
#pragma unroll
        for (int mi = 0; mi < FM; ++mi)
#pragma unroll
            for (int ni = 0; ni < FN; ++ni)
                acc[mi][ni] = __builtin_amdgcn_mfma_f32_16x16x32_bf16(
                    af0[mi], bf0[ni], acc[mi][ni], 0, 0, 0);
        __builtin_amdgcn_s_setprio(0);

        // ---- phase 2: ks1 reads, then free the buffer, stage, compute ----
        bf16x8 af1[FM], bf1[FN];
#pragma unroll
        for (int mi = 0; mi < FM; ++mi) {
            int row = wm * FM * 16 + mi * 16 + li;
            af1[mi] = *(const bf16x8*)&la[row * 64 + ((4 + gk) ^ (row & 7)) * 8];
        }
#pragma unroll
        for (int ni = 0; ni < FN; ++ni) {
            int row = wn * FN * 16 + ni * 16 + li;
            bf1[ni] = *(const bf16x8*)&lb[row * 64 + ((4 + gk) ^ (row & 7)) * 8];
        }
        asm volatile("s_waitcnt lgkmcnt(0)" ::: "memory");  // all ds_reads of buf retired
        __builtin_amdgcn_s_barrier();                        // every wave done with buf
        if (t + 2 < nkt) stage(t + 2, t & 1);                // overlaps MFMA ks1
        __builtin_amdgcn_s_setprio(1);
#pragma unroll
        for (int mi = 0; mi < FM; ++mi)
#pragma unroll
            for (int ni = 0; ni < FN; ++ni)
                acc[mi][ni] = __builtin_amdgcn_mfma_f32_16x16x32_bf16(
                    af1[mi], bf1[ni], acc[mi][ni], 0, 0, 0);
        __builtin_amdgcn_s_setprio(0);
    }

    // epilogue: C/D layout col=lane&15, row=(lane>>4)*4+j
#pragma unroll
    for (int mi = 0; mi < FM; ++mi) {
#pragma unroll
        for (int ni = 0; ni < FN; ++ni) {
            int col = bn + wn * FN * 16 + ni * 16 + li;
            float bv = bias[col];
            int row0 = bm + wm * FM * 16 + mi * 16 + gk * 4;
            if (VT && col >= 2 * cEX) {
                short4 pk;
                pk.x = f2bs(acc[mi][ni][0] + bv);
                pk.y = f2bs(acc[mi][ni][1] + bv);
                pk.z = f2bs(acc[mi][ni][2] + bv);
                pk.w = f2bs(acc[mi][ni][3] + bv);
                *(short4*)&vTr[(size_t)(col - 2 * cEX) * cMP + row0] = pk;
            } else {
#pragma unroll
                for (int j = 0; j < 4; ++j) {
                    int row = row0 + j;
                    float v = acc[mi][ni][j] + bv;
                    if (RELU) v = fmaxf(v, 0.0f);
                    if (RESID) v += resid[(size_t)row * N + col];
                    if (OUTBF16)
                        ((bf16*)Cout)[(size_t)row * N + col] = __float2bfloat16(v);
                    else
                        ((float*)Cout)[(size_t)row * N + col] = v;
                }
            }
        }
    }
}

// ---------------- MFMA flash attention, KVBLK=64 ----------------
// grid (8 qtiles, 12 heads, 8 batch), 4 waves x 16 q-rows; 64-key tiles.
__global__ __launch_bounds__(256) void attn_mfma(
    const short* __restrict__ qkv, const short* __restrict__ vT, bf16* __restrict__ y)
{
    const int qt = blockIdx.x, h = blockIdx.y, b = blockIdx.z;
    __shared__ short Ks[64 * 64];      // [key][d], chunk-swizzled
    __shared__ short Vs[64 * 64];      // [d][key], chunk-swizzled
    __shared__ short Ss[4][16][72];    // per-wave P (bf16), padded rows
    const int tid = threadIdx.x;
    const int lane = tid & 63, wid = tid >> 6;
    const int li = lane & 15, gk = lane >> 4;

    const size_t rowb = (size_t)b * cMB;
    int qr = qt * 64 + wid * 16 + li;
    int qrc = qr < cT ? qr : cT - 1;
    const short* qrow = qkv + (rowb + qrc) * cQKV + h * cHD;
    bf16x8 qf0 = *(const bf16x8*)(qrow + gk * 8);
    bf16x8 qf1 = *(const bf16x8*)(qrow + 32 + gk * 8);

    f32x4 o[4];
    float mrow[4], lrow[4];
#pragma unroll
    for (int dt = 0; dt < 4; ++dt) o[dt] = f32x4{0.f, 0.f, 0.f, 0.f};
#pragma unroll
    for (int j = 0; j < 4; ++j) { mrow[j] = -3e38f; lrow[j] = 0.f; }

    const int qloc = qt * 64 + wid * 16 + gk * 4;

    const int nkt = qt + 1;
    for (int kt = 0; kt < nkt; ++kt) {
        // stage K[64][64] and Vt[64][64]: linear dest, inverse-swizzled source
#pragma unroll
        for (int i = 0; i < 2; ++i) {
            int s = i * 256 + tid;
            int r = s >> 3, c = s & 7;
            gload16(qkv + (rowb + kt * 64 + r) * cQKV + cEX + h * cHD + (c ^ (r & 7)) * 8,
                    (char*)Ks + (size_t)(i * 256 + wid * 64) * 16);
        }
#pragma unroll
        for (int i = 0; i < 2; ++i) {
            int s = i * 256 + tid;
            int d = s >> 3, c = s & 7;
            gload16(vT + (size_t)(h * cHD + d) * cMP + rowb + kt * 64 + (c ^ (d & 7)) * 8,
                    (char*)Vs + (size_t)(i * 256 + wid * 64) * 16);
        }
        __syncthreads();

        // QK^T: 4 key-subtiles of 16, 2 d-halves each
        f32x4 sg[4];
#pragma unroll
        for (int g = 0; g < 4; ++g) sg[g] = f32x4{0.f, 0.f, 0.f, 0.f};
#pragma unroll
        for (int g = 0; g < 4; ++g) {
            int key = g * 16 + li;
            bf16x8 k0 = *(const bf16x8*)&Ks[key * 64 + (gk ^ (key & 7)) * 8];
            bf16x8 k1 = *(const bf16x8*)&Ks[key * 64 + ((4 + gk) ^ (key & 7)) * 8];
            sg[g] = __builtin_amdgcn_mfma_f32_16x16x32_bf16(qf0, k0, sg[g], 0, 0, 0);
            sg[g] = __builtin_amdgcn_mfma_f32_16x16x32_bf16(qf1, k1, sg[g], 0, 0, 0);
        }

        // mask + scale + online softmax (row j, reduce over 16 lanes li)
#pragma unroll
        for (int j = 0; j < 4; ++j) {
            int q = qloc + j;
            float sc[4];
#pragma unroll
            for (int g = 0; g < 4; ++g) {
                int kg = kt * 64 + g * 16 + li;
                sc[g] = (kg <= q) ? sg[g][j] * 0.125f : -3e38f;
            }
            float tm = fmaxf(fmaxf(sc[0], sc[1]), fmaxf(sc[2], sc[3]));
            tm = fmaxf(tm, __shfl_xor(tm, 1, 16));
            tm = fmaxf(tm, __shfl_xor(tm, 2, 16));
            tm = fmaxf(tm, __shfl_xor(tm, 4, 16));
            tm = fmaxf(tm, __shfl_xor(tm, 8, 16));
            float mnew = fmaxf(mrow[j], tm);
            float p[4], ps = 0.f;
#pragma unroll
            for (int g = 0; g < 4; ++g) { p[g] = __expf(sc[g] - mnew); ps += p[g]; }
            ps += __shfl_xor(ps, 1, 16);
            ps += __shfl_xor(ps, 2, 16);
            ps += __shfl_xor(ps, 4, 16);
            ps += __shfl_xor(ps, 8, 16);
            float scale = __expf(mrow[j] - mnew);
            lrow[j] = lrow[j] * scale + ps;
            mrow[j] = mnew;
#pragma unroll
            for (int dt = 0; dt < 4; ++dt) o[dt][j] *= scale;
#pragma unroll
            for (int g = 0; g < 4; ++g)
                Ss[wid][gk * 4 + j][g * 16 + li] = f2bs(p[g]);
        }

        // PV: two 32-key halves
        bf16x8 pa0 = *(const bf16x8*)&Ss[wid][li][gk * 8];
        bf16x8 pa1 = *(const bf16x8*)&Ss[wid][li][32 + gk * 8];
#pragma unroll
        for (int dt = 0; dt < 4; ++dt) {
            int d = dt * 16 + li;
            bf16x8 vf0 = *(const bf16x8*)&Vs[d * 64 + (gk ^ (d & 7)) * 8];
            bf16x8 vf1 = *(const bf16x8*)&Vs[d * 64 + ((4 + gk) ^ (d & 7)) * 8];
            o[dt] = __builtin_amdgcn_mfma_f32_16x16x32_bf16(pa0, vf0, o[dt], 0, 0, 0);
            o[dt] = __builtin_amdgcn_mfma_f32_16x16x32_bf16(pa1, vf1, o[dt], 0, 0, 0);
        }
        __syncthreads();
    }

#pragma unroll
    for (int j = 0; j < 4; ++j) {
        int q = qloc + j;
        if (q >= cT) continue;
        float inv = 1.0f / lrow[j];
        bf16* yr = y + (rowb + q) * cEX + h * cHD;
#pragma unroll
        for (int dt = 0; dt < 4; ++dt)
            yr[dt * 16 + li] = __float2bfloat16(o[dt][j] * inv);
    }
}

// ---------------- head ----------------
__global__ __launch_bounds__(256) void head_part_kernel(
    const float* __restrict__ xf, const float* __restrict__ hw, float* __restrict__ part)
{
    __shared__ float xs[8][1536];
    const int tid = threadIdx.x;
    const int k0 = blockIdx.x * 1536;
    for (int i = tid; i < 8 * 1536; i += 256) {
        int bb = i / 1536, kk = i - bb * 1536;
        xs[bb][kk] = xf[(size_t)bb * (cMB * cEX) + k0 + kk];
    }
    __syncthreads();
    float acc[8] = {};
    const float* wp = hw + (size_t)k0 * cVOC + tid;
    for (int kk = 0; kk < 1536; ++kk) {
        float w = wp[(size_t)kk * cVOC];
#pragma unroll
        for (int bb = 0; bb < 8; ++bb) acc[bb] += xs[bb][kk] * w;
    }
#pragma unroll
    for (int bb = 0; bb < 8; ++bb)
        part[((size_t)blockIdx.x * 8 + bb) * cVOC + tid] = acc[bb];
}

__global__ __launch_bounds__(256) void head_reduce_kernel(
    const float* __restrict__ part, const float* __restrict__ hb, float* __restrict__ out)
{
    int i = blockIdx.x * 256 + threadIdx.x;
    int bb = i >> 8, vv = i & 255;
    float acc = hb[vv];
    for (int c = 0; c < 255; ++c) acc += part[((size_t)c * 8 + bb) * 256 + vv];
    out[i] = acc;
}

// ---------------- launch ----------------
extern "C" void kernel_launch(void* const* d_in, const int* in_sizes, int n_in,
                              void* d_out, int out_size, void* d_ws, size_t ws_size,
                              hipStream_t stream) {
    (void)in_sizes; (void)n_in; (void)out_size; (void)ws_size;
    const int*   idx    = (const int*)d_in[0];
    const float* lin_w  = (const float*)d_in[1];
    const float* lin_b  = (const float*)d_in[2];
    const float* ln1_s  = (const float*)d_in[3];
    const float* ln1_b  = (const float*)d_in[4];
    const float* qw     = (const float*)d_in[5];
    const float* qbias  = (const float*)d_in[6];
    const float* kw     = (const float*)d_in[7];
    const float* kbias  = (const float*)d_in[8];
    const float* vw     = (const float*)d_in[9];
    const float* vbias  = (const float*)d_in[10];
    const float* ew     = (const float*)d_in[11];
    const float* ebias  = (const float*)d_in[12];
    const float* ln2_s  = (const float*)d_in[13];
    const float* ln2_b  = (const float*)d_in[14];
    const float* m1w    = (const float*)d_in[15];
    const float* m1b    = (const float*)d_in[16];
    const float* m2w    = (const float*)d_in[17];
    const float* m2b    = (const float*)d_in[18];
    const float* lnf_s  = (const float*)d_in[19];
    const float* lnf_b  = (const float*)d_in[20];
    const float* head_w = (const float*)d_in[21];
    const float* head_b = (const float*)d_in[22];
    float* out = (float*)d_out;

    const size_t act = (size_t)cMP * cEX;
    float* x    = (float*)d_ws;                    // [4096][768] fp32
    float* xf   = x + act;                         // [4096][768] fp32
    float* part = xf + act;                        // 255*8*256
    float* qkvb = part + 255 * 8 * 256;            // [11][2304]
    short* qkv  = (short*)(qkvb + cNBLK * cQKV);   // [4096][2304] bf16 (V region unused)
    short* vTr  = qkv + (size_t)cMP * cQKV;        // [768][4096] bf16
    short* h    = vTr + (size_t)cEX * cMP;         // [4096][768] bf16
    short* h2   = h + act;
    short* y    = h2 + act;
    short* u    = y + act;                         // [4096][3072] bf16
    short* wqkvT = u + (size_t)cMP * 4 * cEX;      // [11][2304][768]
    short* weT   = wqkvT + (size_t)cNBLK * cQKV * cEX;
    short* wm1T  = weT + (size_t)cNBLK * cEX * cEX;
    short* wm2T  = wm1T + (size_t)cNBLK * cEX * 4 * cEX;

    transpose_w<<<dim3(24, 24, cNBLK), 256, 0, stream>>>(qw, (bf16*)wqkvT, cEX, cEX,
        (size_t)cEX * cEX, (size_t)cQKV * cEX, 0);
    transpose_w<<<dim3(24, 24, cNBLK), 256, 0, stream>>>(kw, (bf16*)wqkvT, cEX, cEX,
        (size_t)cEX * cEX, (size_t)cQKV * cEX, cEX);
    transpose_w<<<dim3(24, 24, cNBLK), 256, 0, stream>>>(vw, (bf16*)wqkvT, cEX, cEX,
        (size_t)cEX * cEX, (size_t)cQKV * cEX, 2 * cEX);
    transpose_w<<<dim3(24, 24, cNBLK), 256, 0, stream>>>(ew, (bf16*)weT, cEX, cEX,
        (size_t)cEX * cEX, (size_t)cEX * cEX, 0);
    transpose_w<<<dim3(96, 24, cNBLK), 256, 0, stream>>>(m1w, (bf16*)wm1T, cEX, 4 * cEX,
        (size_t)cEX * 4 * cEX, (size_t)cEX * 4 * cEX, 0);
    transpose_w<<<dim3(24, 96, cNBLK), 256, 0, stream>>>(m2w, (bf16*)wm2T, 4 * cEX, cEX,
        (size_t)cEX * 4 * cEX, (size_t)cEX * 4 * cEX, 0);
    concat_bias<<<(cNBLK * cQKV + 255) / 256, 256, 0, stream>>>(qbias, kbias, vbias, qkvb);

    embed_kernel<<<cMP, 256, 0, stream>>>(idx, lin_w, lin_b, x);

    for (int blk = 0; blk < cNBLK; ++blk) {
        size_t bo = (size_t)blk * cEX;
        ln_wave<bf16><<<cMP / 4, 256, 0, stream>>>(x, ln1_s + bo, ln1_b + bo, (bf16*)h);
        // QKV fused; V columns written transposed into vTr
        gemm_db<4, 4, false, false, true, true><<<dim3(cQKV / 128, cMP / 128), 256, 0, stream>>>(
            h, wqkvT + (size_t)blk * cQKV * cEX, qkvb + (size_t)blk * cQKV, nullptr,
            qkv, vTr, cEX, cQKV);
        attn_mfma<<<dim3(8, cNH, cB), 256, 0, stream>>>(qkv, vTr, (bf16*)y);
        gemm_db<2, 4, false, true, false, false><<<dim3(cEX / 128, cMP / 64), 256, 0, stream>>>(
            y, weT + (size_t)blk * cEX * cEX, ebias + bo, x, x, nullptr, cEX, cEX);
        ln_wave<bf16><<<cMP / 4, 256, 0, stream>>>(x, ln2_s + bo, ln2_b + bo, (bf16*)h2);
        gemm_db<4, 4, true, false, true, false><<<dim3(4 * cEX / 128, cMP / 128), 256, 0, stream>>>(
            h2, wm1T + (size_t)blk * cEX * 4 * cEX, m1b + (size_t)blk * 4 * cEX, nullptr,
            u, nullptr, cEX, 4 * cEX);
        gemm_db<2, 4, false, true, false, false><<<dim3(cEX / 128, cMP / 64), 256, 0, stream>>>(
            u, wm2T + (size_t)blk * cEX * 4 * cEX, m2b + bo, x, x, nullptr, 4 * cEX, cEX);
    }
    ln_wave<float><<<cMP / 4, 256, 0, stream>>>(x, lnf_s, lnf_b, xf);
    head_part_kernel<<<255, 256, 0, stream>>>(xf, head_w, part);
    head_reduce_kernel<<<8, 256, 0, stream>>>(part, head_b, out);
}